// Round 1
// baseline (4829.128 us; speedup 1.0000x reference)
//
#include <hip/hip_runtime.h>
#include <hip/hip_bf16.h>
#include <math.h>

// Problem constants
#define NLAB 9
#define NL   2
#define DI   768
#define DM   1536
#define DS   16
#define KC   4
#define DD   96
#define BB   2
#define SS   2048
#define TT   (BB*SS)
#define EPSF 1e-6f

__device__ __forceinline__ float siluf(float x) { return x / (1.f + __expf(-x)); }
__device__ __forceinline__ float softplusf(float x) { return x > 15.f ? x : log1pf(__expf(x)); }

// x[t,:] = emb[ids[t],:] * mask[t]   (block = 192 threads, float4 over DI=768)
__global__ void embed_kernel(const int* __restrict__ ids, const int* __restrict__ mask,
                             const float* __restrict__ emb, float* __restrict__ x)
{
    int t = blockIdx.x;
    int i = threadIdx.x;
    float m = (float)mask[t];
    int id = ids[t];
    float4 v = ((const float4*)(emb + (size_t)id * DI))[i];
    v.x *= m; v.y *= m; v.z *= m; v.w *= m;
    ((float4*)(x + (size_t)t * DI))[i] = v;
}

// h[t,:] = x[t,:] * rsqrt(mean(x^2)+eps) * w    (block = 256, one token per block)
__global__ void rmsnorm_kernel(const float* __restrict__ x, const float* __restrict__ w,
                               float* __restrict__ h)
{
    __shared__ float red[4];
    int t = blockIdx.x;
    const float* xr = x + (size_t)t * DI;
    float ss = 0.f;
    for (int i = threadIdx.x; i < DI; i += 256) { float v = xr[i]; ss += v * v; }
    #pragma unroll
    for (int m = 1; m < 64; m <<= 1) ss += __shfl_xor(ss, m, 64);
    if ((threadIdx.x & 63) == 0) red[threadIdx.x >> 6] = ss;
    __syncthreads();
    float scale = rsqrtf((red[0] + red[1] + red[2] + red[3]) * (1.f / DI) + EPSF);
    for (int i = threadIdx.x; i < DI; i += 256)
        h[(size_t)t * DI + i] = xr[i] * scale * w[i];
}

// C[m,n] = act( Amat[m,:]·Bmat[n,:] + bias[n] ) + Rres[m,n]
// NT layout (both K-major). REQUIRES: M%128==0, N%128==0, K%16==0.
// 128x128 tile, BK=16, 256 threads, 8x8 per thread.
__global__ __launch_bounds__(256) void gemm_nt_f32(
    const float* __restrict__ Amat, const float* __restrict__ Bmat,
    const float* __restrict__ Rres, const float* __restrict__ bias,
    float* __restrict__ C, int M, int N, int Kd,
    int lda, int ldb, int ldc, int act)
{
    constexpr int BM = 128, BN = 128, BK = 16;
    __shared__ float As[BK][BM + 4];
    __shared__ float Bs[BK][BN + 4];
    const int tid = threadIdx.x;
    const int bm = blockIdx.y * BM;
    const int bn = blockIdx.x * BN;
    const int ty = tid >> 4, tx = tid & 15;
    float acc[8][8] = {};

    for (int kt = 0; kt < Kd; kt += BK) {
        #pragma unroll
        for (int sidx = 0; sidx < 2; ++sidx) {
            int slot = tid + sidx * 256;        // 512 float4 slots per tile
            int row = slot >> 2;
            int kc = (slot & 3) << 2;
            float4 va = *(const float4*)(Amat + (size_t)(bm + row) * lda + kt + kc);
            As[kc + 0][row] = va.x; As[kc + 1][row] = va.y;
            As[kc + 2][row] = va.z; As[kc + 3][row] = va.w;
            float4 vb = *(const float4*)(Bmat + (size_t)(bn + row) * ldb + kt + kc);
            Bs[kc + 0][row] = vb.x; Bs[kc + 1][row] = vb.y;
            Bs[kc + 2][row] = vb.z; Bs[kc + 3][row] = vb.w;
        }
        __syncthreads();
        #pragma unroll
        for (int kk = 0; kk < BK; ++kk) {
            float a[8], b[8];
            *(float4*)&a[0] = *(const float4*)&As[kk][ty * 8];
            *(float4*)&a[4] = *(const float4*)&As[kk][ty * 8 + 4];
            *(float4*)&b[0] = *(const float4*)&Bs[kk][tx * 8];
            *(float4*)&b[4] = *(const float4*)&Bs[kk][tx * 8 + 4];
            #pragma unroll
            for (int i = 0; i < 8; ++i)
                #pragma unroll
                for (int j = 0; j < 8; ++j)
                    acc[i][j] += a[i] * b[j];
        }
        __syncthreads();
    }
    #pragma unroll
    for (int i = 0; i < 8; ++i) {
        int m = bm + ty * 8 + i;
        #pragma unroll
        for (int j = 0; j < 8; ++j) {
            int n = bn + tx * 8 + j;
            float v = acc[i][j];
            if (bias) v += bias[n];
            if (act == 1) v = softplusf(v);
            if (Rres) v += Rres[(size_t)m * ldc + n];
            C[(size_t)m * ldc + n] = v;
        }
    }
}

// causal depthwise conv (K=4, left pad 3 within each batch) + silu
// grid (TT, DM/256), block 256; reads 'a' half of proj (row stride 2*DM)
__global__ void conv_silu_kernel(const float* __restrict__ proj, const float* __restrict__ cw,
                                 const float* __restrict__ cb, float* __restrict__ aconv)
{
    int t = blockIdx.x;
    int d = blockIdx.y * 256 + threadIdx.x;
    int p = t & (SS - 1);
    float acc = cb[d];
    #pragma unroll
    for (int j = 0; j < KC; ++j) {
        int pp = p - (KC - 1) + j;
        if (pp >= 0)
            acc += cw[d * KC + j] * proj[(size_t)(t - (KC - 1) + j) * (2 * DM) + d];
    }
    aconv[(size_t)t * DM + d] = siluf(acc);
}

// Bm (16), Cm (16), dd1 (96) from aconv row; block=128 (one output each), one token per block
__global__ void skinny_kernel(const float* __restrict__ aconv,
                              const float* __restrict__ WB, const float* __restrict__ WC,
                              const float* __restrict__ W1,
                              float* __restrict__ Bm, float* __restrict__ Cm,
                              float* __restrict__ dd1)
{
    __shared__ float arow[DM];
    int t = blockIdx.x;
    const float* ap = aconv + (size_t)t * DM;
    for (int i = threadIdx.x; i < DM / 4; i += 128)
        ((float4*)arow)[i] = ((const float4*)ap)[i];
    __syncthreads();
    int n = threadIdx.x;
    const float* w;
    float* out;
    size_t oi;
    if (n < 16)      { w = WB + (size_t)n * DM;        out = Bm;  oi = (size_t)t * DS + n; }
    else if (n < 32) { w = WC + (size_t)(n - 16) * DM; out = Cm;  oi = (size_t)t * DS + (n - 16); }
    else             { w = W1 + (size_t)(n - 32) * DM; out = dd1; oi = (size_t)t * DD + (n - 32); }
    float acc = 0.f;
    for (int k = 0; k < DM; k += 4) {
        float4 wv = *(const float4*)(w + k);
        acc += arow[k] * wv.x + arow[k + 1] * wv.y + arow[k + 2] * wv.z + arow[k + 3] * wv.w;
    }
    out[oi] = acc;
}

// selective scan: grid (DM/16, B), block 256 = 16 d-lanes x 16 s-lanes
// y[t,d] = (sum_s hid[t,d,s]*Cm[t,s] + Dp[d]*a[t,d]) * silu(gate[t,d])
__global__ void scan_kernel(const float* __restrict__ aconv, const float* __restrict__ Bm,
                            const float* __restrict__ Cm, const float* __restrict__ delta,
                            const float* __restrict__ proj, const float* __restrict__ Amat,
                            const float* __restrict__ Dp, float* __restrict__ y)
{
    int b = blockIdx.y;
    int d = blockIdx.x * 16 + (threadIdx.x >> 4);
    int s = threadIdx.x & 15;
    float negA = -Amat[(size_t)d * DS + s];
    float Dpd = Dp[d];
    float hid = 0.f;
    for (int t = 0; t < SS; ++t) {
        size_t row = (size_t)b * SS + t;
        float dt = delta[row * DM + d];
        float av = aconv[row * DM + d];
        float Bv = Bm[row * DS + s];
        float Cv = Cm[row * DS + s];
        float Abar = __expf(dt * negA);
        hid = Abar * hid + (dt * av) * Bv;
        float contrib = hid * Cv;
        #pragma unroll
        for (int m = 1; m < 16; m <<= 1) contrib += __shfl_xor(contrib, m, 64);
        if (s == 0) {
            float g = proj[row * (2 * DM) + DM + d];
            y[row * DM + d] = (contrib + Dpd * av) * siluf(g);
        }
    }
}

// logits[t,n] = x[t,:]·cls_w[n,:] + cls_b[n]; one wave per token
__global__ void cls_kernel(const float* __restrict__ x, const float* __restrict__ W,
                           const float* __restrict__ bias, float* __restrict__ out)
{
    int t = blockIdx.x;
    int lane = threadIdx.x;
    const float* xr = x + (size_t)t * DI;
    float acc[NLAB];
    #pragma unroll
    for (int n = 0; n < NLAB; ++n) acc[n] = 0.f;
    for (int i = lane; i < DI; i += 64) {
        float xv = xr[i];
        #pragma unroll
        for (int n = 0; n < NLAB; ++n) acc[n] += xv * W[(size_t)n * DI + i];
    }
    #pragma unroll
    for (int n = 0; n < NLAB; ++n)
        #pragma unroll
        for (int m = 1; m < 64; m <<= 1) acc[n] += __shfl_xor(acc[n], m, 64);
    if (lane < NLAB) out[(size_t)t * NLAB + lane] = acc[lane] + bias[lane];
}

extern "C" void kernel_launch(void* const* d_in, const int* in_sizes, int n_in,
                              void* d_out, int out_size, void* d_ws, size_t ws_size,
                              hipStream_t stream)
{
    const int*   ids    = (const int*)d_in[0];
    const int*   mask   = (const int*)d_in[1];
    const float* emb    = (const float*)d_in[2];
    const float* norm_w = (const float*)d_in[3];
    const float* Wi     = (const float*)d_in[4];
    const float* conv_w = (const float*)d_in[5];
    const float* conv_b = (const float*)d_in[6];
    const float* sB_w   = (const float*)d_in[7];
    const float* sC_w   = (const float*)d_in[8];
    const float* sD1_w  = (const float*)d_in[9];
    const float* sD2_w  = (const float*)d_in[10];
    const float* Amat   = (const float*)d_in[11];
    const float* Dp     = (const float*)d_in[12];
    const float* out_w  = (const float*)d_in[13];
    const float* cls_w  = (const float*)d_in[14];
    const float* cls_b  = (const float*)d_in[15];
    float* logits = (float*)d_out;

    // workspace layout (floats)
    float* ws = (float*)d_ws;
    size_t off = 0;
    float* x     = ws + off; off += (size_t)TT * DI;        // residual stream
    float* proj  = ws + off; off += (size_t)TT * 2 * DM;    // a | gate
    float* aconv = ws + off; off += (size_t)TT * DM;        // silu(conv(a))
    float* delta = ws + off; off += (size_t)TT * DM;
    float* ybuf  = ws + off; off += (size_t)TT * DM;        // also aliases h and dd1
    float* Bmb   = ws + off; off += (size_t)TT * DS;
    float* Cmb   = ws + off; off += (size_t)TT * DS;
    if (ws_size < off * sizeof(float)) return;  // fail loud (output stays wrong)

    float* h   = ybuf;                    // TT*DI, dead before scan writes ybuf
    float* dd1 = ybuf + (size_t)TT * DI;  // TT*DD, dead before scan writes ybuf

    embed_kernel<<<TT, DI / 4, 0, stream>>>(ids, mask, emb, x);

    for (int l = 0; l < NL; ++l) {
        const float* Wi_l  = Wi    + (size_t)l * 2 * DM * DI;
        const float* cw_l  = conv_w + (size_t)l * DM * KC;
        const float* cb_l  = conv_b + (size_t)l * DM;
        const float* WB_l  = sB_w  + (size_t)l * DS * DM;
        const float* WC_l  = sC_w  + (size_t)l * DS * DM;
        const float* W1_l  = sD1_w + (size_t)l * DD * DM;
        const float* W2_l  = sD2_w + (size_t)l * DM * DD;
        const float* A_l   = Amat  + (size_t)l * DM * DS;
        const float* Dp_l  = Dp    + (size_t)l * DM;
        const float* Wo_l  = out_w + (size_t)l * DI * DM;
        const float* nw_l  = norm_w + (size_t)l * DI;

        rmsnorm_kernel<<<TT, 256, 0, stream>>>(x, nw_l, h);

        // proj = h @ Wi^T : M=TT, N=2*DM, K=DI
        gemm_nt_f32<<<dim3(2 * DM / 128, TT / 128), 256, 0, stream>>>(
            h, Wi_l, nullptr, nullptr, proj, TT, 2 * DM, DI, DI, DI, 2 * DM, 0);

        conv_silu_kernel<<<dim3(TT, DM / 256), 256, 0, stream>>>(proj, cw_l, cb_l, aconv);

        skinny_kernel<<<TT, 128, 0, stream>>>(aconv, WB_l, WC_l, W1_l, Bmb, Cmb, dd1);

        // delta = softplus(Dp + dd1 @ W2^T) : M=TT, N=DM, K=DD
        gemm_nt_f32<<<dim3(DM / 128, TT / 128), 256, 0, stream>>>(
            dd1, W2_l, nullptr, Dp_l, delta, TT, DM, DD, DD, DD, DM, 1);

        scan_kernel<<<dim3(DM / 16, BB), 256, 0, stream>>>(
            aconv, Bmb, Cmb, delta, proj, A_l, Dp_l, ybuf);

        // x = x + y @ Wo^T : M=TT, N=DI, K=DM
        gemm_nt_f32<<<dim3(DI / 128, TT / 128), 256, 0, stream>>>(
            ybuf, Wo_l, x, nullptr, x, TT, DI, DM, DM, DM, DI, 0);
    }

    cls_kernel<<<TT, 64, 0, stream>>>(x, cls_w, cls_b, logits);
}

// Round 2
// 2202.297 us; speedup vs baseline: 2.1928x; 2.1928x over previous
//
#include <hip/hip_runtime.h>
#include <hip/hip_bf16.h>
#include <math.h>

// Problem constants
#define NLAB 9
#define NL   2
#define DI   768
#define DM   1536
#define DS   16
#define KC   4
#define DD   96
#define BB   2
#define SS   2048
#define TT   (BB*SS)
#define EPSF 1e-6f

// chunked scan config
#define NCH  32
#define CL   (SS/NCH)   // 64

__device__ __forceinline__ float siluf(float x) { return x / (1.f + __expf(-x)); }
__device__ __forceinline__ float softplusf(float x) { return x > 15.f ? x : log1pf(__expf(x)); }

// x[t,:] = emb[ids[t],:] * mask[t]   (block = 192 threads, float4 over DI=768)
__global__ void embed_kernel(const int* __restrict__ ids, const int* __restrict__ mask,
                             const float* __restrict__ emb, float* __restrict__ x)
{
    int t = blockIdx.x;
    int i = threadIdx.x;
    float m = (float)mask[t];
    int id = ids[t];
    float4 v = ((const float4*)(emb + (size_t)id * DI))[i];
    v.x *= m; v.y *= m; v.z *= m; v.w *= m;
    ((float4*)(x + (size_t)t * DI))[i] = v;
}

// h[t,:] = x[t,:] * rsqrt(mean(x^2)+eps) * w    (block = 256, one token per block)
__global__ void rmsnorm_kernel(const float* __restrict__ x, const float* __restrict__ w,
                               float* __restrict__ h)
{
    __shared__ float red[4];
    int t = blockIdx.x;
    const float* xr = x + (size_t)t * DI;
    float ss = 0.f;
    for (int i = threadIdx.x; i < DI; i += 256) { float v = xr[i]; ss += v * v; }
    #pragma unroll
    for (int m = 1; m < 64; m <<= 1) ss += __shfl_xor(ss, m, 64);
    if ((threadIdx.x & 63) == 0) red[threadIdx.x >> 6] = ss;
    __syncthreads();
    float scale = rsqrtf((red[0] + red[1] + red[2] + red[3]) * (1.f / DI) + EPSF);
    for (int i = threadIdx.x; i < DI; i += 256)
        h[(size_t)t * DI + i] = xr[i] * scale * w[i];
}

// C[m,n] = act( Amat[m,:]·Bmat[n,:] + bias[n] ) + Rres[m,n]
// NT layout (both K-major). REQUIRES: M%128==0, N%128==0, K%16==0.
// 128x128 tile, BK=16, 256 threads, 8x8 per thread.
__global__ __launch_bounds__(256) void gemm_nt_f32(
    const float* __restrict__ Amat, const float* __restrict__ Bmat,
    const float* __restrict__ Rres, const float* __restrict__ bias,
    float* __restrict__ C, int M, int N, int Kd,
    int lda, int ldb, int ldc, int act)
{
    constexpr int BM = 128, BN = 128, BK = 16;
    __shared__ float As[BK][BM + 4];
    __shared__ float Bs[BK][BN + 4];
    const int tid = threadIdx.x;
    const int bm = blockIdx.y * BM;
    const int bn = blockIdx.x * BN;
    const int ty = tid >> 4, tx = tid & 15;
    float acc[8][8] = {};

    for (int kt = 0; kt < Kd; kt += BK) {
        #pragma unroll
        for (int sidx = 0; sidx < 2; ++sidx) {
            int slot = tid + sidx * 256;        // 512 float4 slots per tile
            int row = slot >> 2;
            int kc = (slot & 3) << 2;
            float4 va = *(const float4*)(Amat + (size_t)(bm + row) * lda + kt + kc);
            As[kc + 0][row] = va.x; As[kc + 1][row] = va.y;
            As[kc + 2][row] = va.z; As[kc + 3][row] = va.w;
            float4 vb = *(const float4*)(Bmat + (size_t)(bn + row) * ldb + kt + kc);
            Bs[kc + 0][row] = vb.x; Bs[kc + 1][row] = vb.y;
            Bs[kc + 2][row] = vb.z; Bs[kc + 3][row] = vb.w;
        }
        __syncthreads();
        #pragma unroll
        for (int kk = 0; kk < BK; ++kk) {
            float a[8], b[8];
            *(float4*)&a[0] = *(const float4*)&As[kk][ty * 8];
            *(float4*)&a[4] = *(const float4*)&As[kk][ty * 8 + 4];
            *(float4*)&b[0] = *(const float4*)&Bs[kk][tx * 8];
            *(float4*)&b[4] = *(const float4*)&Bs[kk][tx * 8 + 4];
            #pragma unroll
            for (int i = 0; i < 8; ++i)
                #pragma unroll
                for (int j = 0; j < 8; ++j)
                    acc[i][j] += a[i] * b[j];
        }
        __syncthreads();
    }
    #pragma unroll
    for (int i = 0; i < 8; ++i) {
        int m = bm + ty * 8 + i;
        #pragma unroll
        for (int j = 0; j < 8; ++j) {
            int n = bn + tx * 8 + j;
            float v = acc[i][j];
            if (bias) v += bias[n];
            if (act == 1) v = softplusf(v);
            if (Rres) v += Rres[(size_t)m * ldc + n];
            C[(size_t)m * ldc + n] = v;
        }
    }
}

// causal depthwise conv (K=4, left pad 3 within each batch) + silu
// grid (TT, DM/256), block 256; reads 'a' half of proj (row stride 2*DM)
__global__ void conv_silu_kernel(const float* __restrict__ proj, const float* __restrict__ cw,
                                 const float* __restrict__ cb, float* __restrict__ aconv)
{
    int t = blockIdx.x;
    int d = blockIdx.y * 256 + threadIdx.x;
    int p = t & (SS - 1);
    float acc = cb[d];
    #pragma unroll
    for (int j = 0; j < KC; ++j) {
        int pp = p - (KC - 1) + j;
        if (pp >= 0)
            acc += cw[d * KC + j] * proj[(size_t)(t - (KC - 1) + j) * (2 * DM) + d];
    }
    aconv[(size_t)t * DM + d] = siluf(acc);
}

// Bm (16), Cm (16), dd1 (96) from aconv row; block=128 (one output each), one token per block
__global__ void skinny_kernel(const float* __restrict__ aconv,
                              const float* __restrict__ WB, const float* __restrict__ WC,
                              const float* __restrict__ W1,
                              float* __restrict__ Bm, float* __restrict__ Cm,
                              float* __restrict__ dd1)
{
    __shared__ float arow[DM];
    int t = blockIdx.x;
    const float* ap = aconv + (size_t)t * DM;
    for (int i = threadIdx.x; i < DM / 4; i += 128)
        ((float4*)arow)[i] = ((const float4*)ap)[i];
    __syncthreads();
    int n = threadIdx.x;
    const float* w;
    float* out;
    size_t oi;
    if (n < 16)      { w = WB + (size_t)n * DM;        out = Bm;  oi = (size_t)t * DS + n; }
    else if (n < 32) { w = WC + (size_t)(n - 16) * DM; out = Cm;  oi = (size_t)t * DS + (n - 16); }
    else             { w = W1 + (size_t)(n - 32) * DM; out = dd1; oi = (size_t)t * DD + (n - 32); }
    float acc = 0.f;
    for (int k = 0; k < DM; k += 4) {
        float4 wv = *(const float4*)(w + k);
        acc += arow[k] * wv.x + arow[k + 1] * wv.y + arow[k + 2] * wv.z + arow[k + 3] * wv.w;
    }
    out[oi] = acc;
}

// ---- chunk-parallel selective scan (3 passes) ----
// chain recurrence: hid = exp(dt*negA)*hid + dt*av*Bv
// pass 1: per (b, chunk, d-slice): local scan from 0 -> aggregate (P=prod Abar, Q=final hid)
// pass 2: per chain: serial carry scan over 32 chunks; carry-in stored in-place over P
// pass 3: per (b, chunk, d-slice): re-run recurrence seeded with carry, emit y

// PQ layout: [(b*NCH + c)*DM + d]*DS + s  as float2 {P, Q}; pass2 rewrites .x = carry-in
__global__ __launch_bounds__(256) void scan_pass1(
    const float* __restrict__ delta, const float* __restrict__ aconv,
    const float* __restrict__ Bm, const float* __restrict__ Amat,
    float2* __restrict__ PQ)
{
    __shared__ float sd[CL][16], sa[CL][16], sb[CL][16];
    int b = blockIdx.z, c = blockIdx.y;
    int d0 = blockIdx.x * 16;
    int tid = threadIdx.x;
    int dl = tid >> 4, s = tid & 15;
    size_t rowbase = (size_t)b * SS + (size_t)c * CL;

    for (int i = tid; i < CL * 16; i += 256) {
        int tt = i >> 4, dc = i & 15;
        sd[tt][dc] = delta[(rowbase + tt) * DM + d0 + dc];
        sa[tt][dc] = aconv[(rowbase + tt) * DM + d0 + dc];
        ((float*)sb)[i] = Bm[rowbase * DS + i];   // Bm chunk is fully contiguous
    }
    __syncthreads();

    int d = d0 + dl;
    float negA = -Amat[(size_t)d * DS + s];
    float P = 1.f, hid = 0.f;
    for (int t = 0; t < CL; ++t) {
        float dt = sd[t][dl];
        float av = sa[t][dl];
        float Abar = __expf(dt * negA);
        hid = Abar * hid + (dt * av) * sb[t][s];
        P *= Abar;
    }
    PQ[((size_t)(b * NCH + c) * DM + d) * DS + s] = make_float2(P, hid);
}

// 49152 chains, 32 sequential chunk steps each
__global__ void scan_carry(float2* __restrict__ PQ)
{
    int idx = blockIdx.x * 256 + threadIdx.x;      // over B*DM*DS
    int b = idx / (DM * DS);
    int r = idx - b * (DM * DS);
    float carry = 0.f;
    for (int c = 0; c < NCH; ++c) {
        size_t o = (size_t)(b * NCH + c) * (DM * DS) + r;
        float2 pq = PQ[o];
        PQ[o].x = carry;                           // carry-in for chunk c
        carry = pq.x * carry + pq.y;
    }
}

__global__ __launch_bounds__(256) void scan_pass2(
    const float* __restrict__ delta, const float* __restrict__ aconv,
    const float* __restrict__ Bm, const float* __restrict__ Cm,
    const float* __restrict__ proj, const float* __restrict__ Amat,
    const float* __restrict__ Dp, const float2* __restrict__ PQ,
    float* __restrict__ y)
{
    __shared__ float sd[CL][16], sa[CL][16], sb[CL][16], sc[CL][16], sg[CL][16], sy[CL][16];
    int b = blockIdx.z, c = blockIdx.y;
    int d0 = blockIdx.x * 16;
    int tid = threadIdx.x;
    int dl = tid >> 4, s = tid & 15;
    size_t rowbase = (size_t)b * SS + (size_t)c * CL;

    for (int i = tid; i < CL * 16; i += 256) {
        int tt = i >> 4, dc = i & 15;
        size_t row = rowbase + tt;
        sd[tt][dc] = delta[row * DM + d0 + dc];
        sa[tt][dc] = aconv[row * DM + d0 + dc];
        sg[tt][dc] = proj[row * (2 * DM) + DM + d0 + dc];
        ((float*)sb)[i] = Bm[rowbase * DS + i];
        ((float*)sc)[i] = Cm[rowbase * DS + i];
    }
    __syncthreads();

    int d = d0 + dl;
    float negA = -Amat[(size_t)d * DS + s];
    float Dpd = Dp[d];
    float hid = PQ[((size_t)(b * NCH + c) * DM + d) * DS + s].x;  // carry-in
    for (int t = 0; t < CL; ++t) {
        float dt = sd[t][dl];
        float av = sa[t][dl];
        float Abar = __expf(dt * negA);
        hid = Abar * hid + (dt * av) * sb[t][s];
        float contrib = hid * sc[t][s];
        #pragma unroll
        for (int m = 1; m < 16; m <<= 1) contrib += __shfl_xor(contrib, m, 64);
        if (s == 0)
            sy[t][dl] = (contrib + Dpd * av) * siluf(sg[t][dl]);
    }
    __syncthreads();
    for (int i = tid; i < CL * 16; i += 256)
        y[(rowbase + (i >> 4)) * DM + d0 + (i & 15)] = ((float*)sy)[i];
}

// logits[t,n] = x[t,:]·cls_w[n,:] + cls_b[n]; one wave per token
__global__ void cls_kernel(const float* __restrict__ x, const float* __restrict__ W,
                           const float* __restrict__ bias, float* __restrict__ out)
{
    int t = blockIdx.x;
    int lane = threadIdx.x;
    const float* xr = x + (size_t)t * DI;
    float acc[NLAB];
    #pragma unroll
    for (int n = 0; n < NLAB; ++n) acc[n] = 0.f;
    for (int i = lane; i < DI; i += 64) {
        float xv = xr[i];
        #pragma unroll
        for (int n = 0; n < NLAB; ++n) acc[n] += xv * W[(size_t)n * DI + i];
    }
    #pragma unroll
    for (int n = 0; n < NLAB; ++n)
        #pragma unroll
        for (int m = 1; m < 64; m <<= 1) acc[n] += __shfl_xor(acc[n], m, 64);
    if (lane < NLAB) out[(size_t)t * NLAB + lane] = acc[lane] + bias[lane];
}

extern "C" void kernel_launch(void* const* d_in, const int* in_sizes, int n_in,
                              void* d_out, int out_size, void* d_ws, size_t ws_size,
                              hipStream_t stream)
{
    const int*   ids    = (const int*)d_in[0];
    const int*   mask   = (const int*)d_in[1];
    const float* emb    = (const float*)d_in[2];
    const float* norm_w = (const float*)d_in[3];
    const float* Wi     = (const float*)d_in[4];
    const float* conv_w = (const float*)d_in[5];
    const float* conv_b = (const float*)d_in[6];
    const float* sB_w   = (const float*)d_in[7];
    const float* sC_w   = (const float*)d_in[8];
    const float* sD1_w  = (const float*)d_in[9];
    const float* sD2_w  = (const float*)d_in[10];
    const float* Amat   = (const float*)d_in[11];
    const float* Dp     = (const float*)d_in[12];
    const float* out_w  = (const float*)d_in[13];
    const float* cls_w  = (const float*)d_in[14];
    const float* cls_b  = (const float*)d_in[15];
    float* logits = (float*)d_out;

    // workspace layout (floats)
    float* ws = (float*)d_ws;
    size_t off = 0;
    float* x     = ws + off; off += (size_t)TT * DI;        // residual stream
    float* proj  = ws + off; off += (size_t)TT * 2 * DM;    // a | gate
    float* aconv = ws + off; off += (size_t)TT * DM;        // silu(conv(a))
    float* delta = ws + off; off += (size_t)TT * DM;
    float* ybuf  = ws + off; off += (size_t)TT * DM;        // also aliases h and dd1
    float* Bmb   = ws + off; off += (size_t)TT * DS;
    float* Cmb   = ws + off; off += (size_t)TT * DS;
    float2* PQ   = (float2*)(ws + off); off += (size_t)BB * NCH * DM * DS * 2;
    if (ws_size < off * sizeof(float)) return;  // fail loud (output stays wrong)

    float* h   = ybuf;                    // TT*DI, dead before scan writes ybuf
    float* dd1 = ybuf + (size_t)TT * DI;  // TT*DD, dead before scan writes ybuf

    embed_kernel<<<TT, DI / 4, 0, stream>>>(ids, mask, emb, x);

    for (int l = 0; l < NL; ++l) {
        const float* Wi_l  = Wi    + (size_t)l * 2 * DM * DI;
        const float* cw_l  = conv_w + (size_t)l * DM * KC;
        const float* cb_l  = conv_b + (size_t)l * DM;
        const float* WB_l  = sB_w  + (size_t)l * DS * DM;
        const float* WC_l  = sC_w  + (size_t)l * DS * DM;
        const float* W1_l  = sD1_w + (size_t)l * DD * DM;
        const float* W2_l  = sD2_w + (size_t)l * DM * DD;
        const float* A_l   = Amat  + (size_t)l * DM * DS;
        const float* Dp_l  = Dp    + (size_t)l * DM;
        const float* Wo_l  = out_w + (size_t)l * DI * DM;
        const float* nw_l  = norm_w + (size_t)l * DI;

        rmsnorm_kernel<<<TT, 256, 0, stream>>>(x, nw_l, h);

        // proj = h @ Wi^T : M=TT, N=2*DM, K=DI
        gemm_nt_f32<<<dim3(2 * DM / 128, TT / 128), 256, 0, stream>>>(
            h, Wi_l, nullptr, nullptr, proj, TT, 2 * DM, DI, DI, DI, 2 * DM, 0);

        conv_silu_kernel<<<dim3(TT, DM / 256), 256, 0, stream>>>(proj, cw_l, cb_l, aconv);

        skinny_kernel<<<TT, 128, 0, stream>>>(aconv, WB_l, WC_l, W1_l, Bmb, Cmb, dd1);

        // delta = softplus(Dp + dd1 @ W2^T) : M=TT, N=DM, K=DD
        gemm_nt_f32<<<dim3(DM / 128, TT / 128), 256, 0, stream>>>(
            dd1, W2_l, nullptr, Dp_l, delta, TT, DM, DD, DD, DD, DM, 1);

        // chunk-parallel scan
        scan_pass1<<<dim3(DM / 16, NCH, BB), 256, 0, stream>>>(
            delta, aconv, Bmb, A_l, PQ);
        scan_carry<<<BB * DM * DS / 256, 256, 0, stream>>>(PQ);
        scan_pass2<<<dim3(DM / 16, NCH, BB), 256, 0, stream>>>(
            delta, aconv, Bmb, Cmb, proj, A_l, Dp_l, PQ, ybuf);

        // x = x + y @ Wo^T : M=TT, N=DI, K=DM
        gemm_nt_f32<<<dim3(DI / 128, TT / 128), 256, 0, stream>>>(
            ybuf, Wo_l, x, nullptr, x, TT, DI, DM, DM, DM, DI, 0);
    }

    cls_kernel<<<TT, 64, 0, stream>>>(x, cls_w, cls_b, logits);
}

// Round 3
// 1664.941 us; speedup vs baseline: 2.9005x; 1.3227x over previous
//
#include <hip/hip_runtime.h>
#include <hip/hip_bf16.h>
#include <math.h>

// Problem constants
#define NLAB 9
#define NL   2
#define DI   768
#define DM   1536
#define DS   16
#define KC   4
#define DD   96
#define BB   2
#define SS   2048
#define TT   (BB*SS)
#define EPSF 1e-6f

// chunked scan config
#define NCH  32
#define CL   (SS/NCH)   // 64

// skinny fused projection width: 16 (B) + 16 (C) + 96 (dd1)
#define NW   128

__device__ __forceinline__ float siluf(float x) { return x / (1.f + __expf(-x)); }
__device__ __forceinline__ float softplusf(float x) { return x > 15.f ? x : log1pf(__expf(x)); }

// x[t,:] = emb[ids[t],:] * mask[t]   (block = 192 threads, float4 over DI=768)
__global__ void embed_kernel(const int* __restrict__ ids, const int* __restrict__ mask,
                             const float* __restrict__ emb, float* __restrict__ x)
{
    int t = blockIdx.x;
    int i = threadIdx.x;
    float m = (float)mask[t];
    int id = ids[t];
    float4 v = ((const float4*)(emb + (size_t)id * DI))[i];
    v.x *= m; v.y *= m; v.z *= m; v.w *= m;
    ((float4*)(x + (size_t)t * DI))[i] = v;
}

// h[t,:] = x[t,:] * rsqrt(mean(x^2)+eps) * w    (block = 256, one token per block)
__global__ void rmsnorm_kernel(const float* __restrict__ x, const float* __restrict__ w,
                               float* __restrict__ h)
{
    __shared__ float red[4];
    int t = blockIdx.x;
    const float* xr = x + (size_t)t * DI;
    float ss = 0.f;
    for (int i = threadIdx.x; i < DI; i += 256) { float v = xr[i]; ss += v * v; }
    #pragma unroll
    for (int m = 1; m < 64; m <<= 1) ss += __shfl_xor(ss, m, 64);
    if ((threadIdx.x & 63) == 0) red[threadIdx.x >> 6] = ss;
    __syncthreads();
    float scale = rsqrtf((red[0] + red[1] + red[2] + red[3]) * (1.f / DI) + EPSF);
    for (int i = threadIdx.x; i < DI; i += 256)
        h[(size_t)t * DI + i] = xr[i] * scale * w[i];
}

// C[m,n] = act( Amat[m,:]·Bmat[n,:] + bias[n] ) + Rres[m,n]
// NT layout (both K-major). REQUIRES: M%128==0, N%128==0, K%16==0.
// 128x128 tile, BK=16, 256 threads, 8x8 per thread.
__global__ __launch_bounds__(256) void gemm_nt_f32(
    const float* __restrict__ Amat, const float* __restrict__ Bmat,
    const float* __restrict__ Rres, const float* __restrict__ bias,
    float* __restrict__ C, int M, int N, int Kd,
    int lda, int ldb, int ldc, int act)
{
    constexpr int BM = 128, BN = 128, BK = 16;
    __shared__ float As[BK][BM + 4];
    __shared__ float Bs[BK][BN + 4];
    const int tid = threadIdx.x;
    const int bm = blockIdx.y * BM;
    const int bn = blockIdx.x * BN;
    const int ty = tid >> 4, tx = tid & 15;
    float acc[8][8] = {};

    for (int kt = 0; kt < Kd; kt += BK) {
        #pragma unroll
        for (int sidx = 0; sidx < 2; ++sidx) {
            int slot = tid + sidx * 256;        // 512 float4 slots per tile
            int row = slot >> 2;
            int kc = (slot & 3) << 2;
            float4 va = *(const float4*)(Amat + (size_t)(bm + row) * lda + kt + kc);
            As[kc + 0][row] = va.x; As[kc + 1][row] = va.y;
            As[kc + 2][row] = va.z; As[kc + 3][row] = va.w;
            float4 vb = *(const float4*)(Bmat + (size_t)(bn + row) * ldb + kt + kc);
            Bs[kc + 0][row] = vb.x; Bs[kc + 1][row] = vb.y;
            Bs[kc + 2][row] = vb.z; Bs[kc + 3][row] = vb.w;
        }
        __syncthreads();
        #pragma unroll
        for (int kk = 0; kk < BK; ++kk) {
            float a[8], b[8];
            *(float4*)&a[0] = *(const float4*)&As[kk][ty * 8];
            *(float4*)&a[4] = *(const float4*)&As[kk][ty * 8 + 4];
            *(float4*)&b[0] = *(const float4*)&Bs[kk][tx * 8];
            *(float4*)&b[4] = *(const float4*)&Bs[kk][tx * 8 + 4];
            #pragma unroll
            for (int i = 0; i < 8; ++i)
                #pragma unroll
                for (int j = 0; j < 8; ++j)
                    acc[i][j] += a[i] * b[j];
        }
        __syncthreads();
    }
    #pragma unroll
    for (int i = 0; i < 8; ++i) {
        int m = bm + ty * 8 + i;
        #pragma unroll
        for (int j = 0; j < 8; ++j) {
            int n = bn + tx * 8 + j;
            float v = acc[i][j];
            if (bias) v += bias[n];
            if (act == 1) v = softplusf(v);
            if (Rres) v += Rres[(size_t)m * ldc + n];
            C[(size_t)m * ldc + n] = v;
        }
    }
}

// causal depthwise conv (K=4, left pad 3 within each batch) + silu
// grid (TT, DM/256), block 256; reads 'a' half of proj (row stride 2*DM)
__global__ void conv_silu_kernel(const float* __restrict__ proj, const float* __restrict__ cw,
                                 const float* __restrict__ cb, float* __restrict__ aconv)
{
    int t = blockIdx.x;
    int d = blockIdx.y * 256 + threadIdx.x;
    int p = t & (SS - 1);
    float acc = cb[d];
    #pragma unroll
    for (int j = 0; j < KC; ++j) {
        int pp = p - (KC - 1) + j;
        if (pp >= 0)
            acc += cw[d * KC + j] * proj[(size_t)(t - (KC - 1) + j) * (2 * DM) + d];
    }
    aconv[(size_t)t * DM + d] = siluf(acc);
}

// pack [WB;WC;W1] -> Wcat[l][128][DM]; grid (128, NL), block 256
__global__ void concat_w_kernel(const float* __restrict__ WB, const float* __restrict__ WC,
                                const float* __restrict__ W1, float* __restrict__ Wcat)
{
    int l = blockIdx.y;
    int row = blockIdx.x;
    const float* src;
    if (row < 16)      src = WB + (size_t)l * DS * DM + (size_t)row * DM;
    else if (row < 32) src = WC + (size_t)l * DS * DM + (size_t)(row - 16) * DM;
    else               src = W1 + (size_t)l * DD * DM + (size_t)(row - 32) * DM;
    float* dst = Wcat + ((size_t)l * NW + row) * DM;
    for (int i = threadIdx.x; i < DM / 4; i += 256)
        ((float4*)dst)[i] = ((const float4*)src)[i];
}

// BCD[t][0:16]=Bm, [16:32]=Cm, [32:128]=dd1 : BCD = aconv @ Wcat^T
// M=TT, N=128, K=DM. BM=32, BN=128, BK=32, 256 threads, 4x4/thread, 128 blocks.
__global__ __launch_bounds__(256) void gemm_skinny(
    const float* __restrict__ Amat, const float* __restrict__ Bmat,
    float* __restrict__ C)
{
    constexpr int BM = 32, BN = 128, BK = 32;
    __shared__ float As[BK][BM + 4];
    __shared__ float Bs[BK][BN + 4];
    const int tid = threadIdx.x;
    const int bm = blockIdx.x * BM;
    const int ty = tid >> 5, tx = tid & 31;   // 8 x 32
    float acc[4][4] = {};

    for (int kt = 0; kt < DM; kt += BK) {
        {   // A tile: 32 rows x 8 float4 = 256 slots
            int row = tid >> 3, kc = (tid & 7) << 2;
            float4 va = *(const float4*)(Amat + (size_t)(bm + row) * DM + kt + kc);
            As[kc + 0][row] = va.x; As[kc + 1][row] = va.y;
            As[kc + 2][row] = va.z; As[kc + 3][row] = va.w;
        }
        #pragma unroll
        for (int sidx = 0; sidx < 4; ++sidx) {   // B tile: 128 rows x 8 float4 = 1024 slots
            int slot = tid + sidx * 256;
            int row = slot >> 3, kc = (slot & 7) << 2;
            float4 vb = *(const float4*)(Bmat + (size_t)row * DM + kt + kc);
            Bs[kc + 0][row] = vb.x; Bs[kc + 1][row] = vb.y;
            Bs[kc + 2][row] = vb.z; Bs[kc + 3][row] = vb.w;
        }
        __syncthreads();
        #pragma unroll
        for (int kk = 0; kk < BK; ++kk) {
            float4 a = *(const float4*)&As[kk][ty * 4];
            float4 b = *(const float4*)&Bs[kk][tx * 4];
            float av[4] = {a.x, a.y, a.z, a.w};
            float bv[4] = {b.x, b.y, b.z, b.w};
            #pragma unroll
            for (int i = 0; i < 4; ++i)
                #pragma unroll
                for (int j = 0; j < 4; ++j)
                    acc[i][j] += av[i] * bv[j];
        }
        __syncthreads();
    }
    #pragma unroll
    for (int i = 0; i < 4; ++i) {
        float4 v = make_float4(acc[i][0], acc[i][1], acc[i][2], acc[i][3]);
        *(float4*)(C + (size_t)(bm + ty * 4 + i) * NW + tx * 4) = v;
    }
}

// ---- chunk-parallel selective scan (3 passes) ----
// chain recurrence: hid = exp(dt*negA)*hid + dt*av*Bv
// PQ layout: [(b*NCH + c)*DM + d]*DS + s  as float2 {P, Q}; carry pass rewrites .x = carry-in
__global__ __launch_bounds__(256) void scan_pass1(
    const float* __restrict__ delta, const float* __restrict__ aconv,
    const float* __restrict__ BCD, const float* __restrict__ Amat,
    float2* __restrict__ PQ)
{
    __shared__ float sd[CL][16], sa[CL][16], sb[CL][16];
    int b = blockIdx.z, c = blockIdx.y;
    int d0 = blockIdx.x * 16;
    int tid = threadIdx.x;
    int dl = tid >> 4, s = tid & 15;
    size_t rowbase = (size_t)b * SS + (size_t)c * CL;

    for (int i = tid; i < CL * 16; i += 256) {
        int tt = i >> 4, dc = i & 15;
        sd[tt][dc] = delta[(rowbase + tt) * DM + d0 + dc];
        sa[tt][dc] = aconv[(rowbase + tt) * DM + d0 + dc];
        ((float*)sb)[i] = BCD[(rowbase + tt) * NW + dc];       // Bm = cols 0..15
    }
    __syncthreads();

    int d = d0 + dl;
    float negA = -Amat[(size_t)d * DS + s];
    float P = 1.f, hid = 0.f;
    for (int t = 0; t < CL; ++t) {
        float dt = sd[t][dl];
        float av = sa[t][dl];
        float Abar = __expf(dt * negA);
        hid = Abar * hid + (dt * av) * sb[t][s];
        P *= Abar;
    }
    PQ[((size_t)(b * NCH + c) * DM + d) * DS + s] = make_float2(P, hid);
}

// 49152 chains, 32 sequential chunk steps each
__global__ void scan_carry(float2* __restrict__ PQ)
{
    int idx = blockIdx.x * 256 + threadIdx.x;      // over B*DM*DS
    int b = idx / (DM * DS);
    int r = idx - b * (DM * DS);
    float carry = 0.f;
    for (int c = 0; c < NCH; ++c) {
        size_t o = (size_t)(b * NCH + c) * (DM * DS) + r;
        float2 pq = PQ[o];
        PQ[o].x = carry;                           // carry-in for chunk c
        carry = pq.x * carry + pq.y;
    }
}

__global__ __launch_bounds__(256) void scan_pass2(
    const float* __restrict__ delta, const float* __restrict__ aconv,
    const float* __restrict__ BCD,
    const float* __restrict__ proj, const float* __restrict__ Amat,
    const float* __restrict__ Dp, const float2* __restrict__ PQ,
    float* __restrict__ y)
{
    __shared__ float sd[CL][16], sa[CL][16], sb[CL][16], sc[CL][16], sg[CL][16], sy[CL][16];
    int b = blockIdx.z, c = blockIdx.y;
    int d0 = blockIdx.x * 16;
    int tid = threadIdx.x;
    int dl = tid >> 4, s = tid & 15;
    size_t rowbase = (size_t)b * SS + (size_t)c * CL;

    for (int i = tid; i < CL * 16; i += 256) {
        int tt = i >> 4, dc = i & 15;
        size_t row = rowbase + tt;
        sd[tt][dc] = delta[row * DM + d0 + dc];
        sa[tt][dc] = aconv[row * DM + d0 + dc];
        sg[tt][dc] = proj[row * (2 * DM) + DM + d0 + dc];
        ((float*)sb)[i] = BCD[row * NW + dc];          // Bm
        ((float*)sc)[i] = BCD[row * NW + 16 + dc];     // Cm
    }
    __syncthreads();

    int d = d0 + dl;
    float negA = -Amat[(size_t)d * DS + s];
    float Dpd = Dp[d];
    float hid = PQ[((size_t)(b * NCH + c) * DM + d) * DS + s].x;  // carry-in
    for (int t = 0; t < CL; ++t) {
        float dt = sd[t][dl];
        float av = sa[t][dl];
        float Abar = __expf(dt * negA);
        hid = Abar * hid + (dt * av) * sb[t][s];
        float contrib = hid * sc[t][s];
        #pragma unroll
        for (int m = 1; m < 16; m <<= 1) contrib += __shfl_xor(contrib, m, 64);
        if (s == 0)
            sy[t][dl] = (contrib + Dpd * av) * siluf(sg[t][dl]);
    }
    __syncthreads();
    for (int i = tid; i < CL * 16; i += 256)
        y[(rowbase + (i >> 4)) * DM + d0 + (i & 15)] = ((float*)sy)[i];
}

// logits[t,n] = x[t,:]·cls_w[n,:] + cls_b[n]; one wave per token
__global__ void cls_kernel(const float* __restrict__ x, const float* __restrict__ W,
                           const float* __restrict__ bias, float* __restrict__ out)
{
    int t = blockIdx.x;
    int lane = threadIdx.x;
    const float* xr = x + (size_t)t * DI;
    float acc[NLAB];
    #pragma unroll
    for (int n = 0; n < NLAB; ++n) acc[n] = 0.f;
    for (int i = lane; i < DI; i += 64) {
        float xv = xr[i];
        #pragma unroll
        for (int n = 0; n < NLAB; ++n) acc[n] += xv * W[(size_t)n * DI + i];
    }
    #pragma unroll
    for (int n = 0; n < NLAB; ++n)
        #pragma unroll
        for (int m = 1; m < 64; m <<= 1) acc[n] += __shfl_xor(acc[n], m, 64);
    if (lane < NLAB) out[(size_t)t * NLAB + lane] = acc[lane] + bias[lane];
}

extern "C" void kernel_launch(void* const* d_in, const int* in_sizes, int n_in,
                              void* d_out, int out_size, void* d_ws, size_t ws_size,
                              hipStream_t stream)
{
    const int*   ids    = (const int*)d_in[0];
    const int*   mask   = (const int*)d_in[1];
    const float* emb    = (const float*)d_in[2];
    const float* norm_w = (const float*)d_in[3];
    const float* Wi     = (const float*)d_in[4];
    const float* conv_w = (const float*)d_in[5];
    const float* conv_b = (const float*)d_in[6];
    const float* sB_w   = (const float*)d_in[7];
    const float* sC_w   = (const float*)d_in[8];
    const float* sD1_w  = (const float*)d_in[9];
    const float* sD2_w  = (const float*)d_in[10];
    const float* Amat   = (const float*)d_in[11];
    const float* Dp     = (const float*)d_in[12];
    const float* out_w  = (const float*)d_in[13];
    const float* cls_w  = (const float*)d_in[14];
    const float* cls_b  = (const float*)d_in[15];
    float* logits = (float*)d_out;

    // workspace layout (floats)
    float* ws = (float*)d_ws;
    size_t off = 0;
    float* x     = ws + off; off += (size_t)TT * DI;        // residual stream
    float* proj  = ws + off; off += (size_t)TT * 2 * DM;    // a | gate
    float* aconv = ws + off; off += (size_t)TT * DM;        // silu(conv(a))
    float* delta = ws + off; off += (size_t)TT * DM;
    float* ybuf  = ws + off; off += (size_t)TT * DM;        // also aliases h
    float* BCD   = ws + off; off += (size_t)TT * NW;        // Bm|Cm|dd1 fused
    float* Wcat  = ws + off; off += (size_t)NL * NW * DM;   // packed [WB;WC;W1]
    float2* PQ   = (float2*)(ws + off); off += (size_t)BB * NCH * DM * DS * 2;
    if (ws_size < off * sizeof(float)) return;  // fail loud (output stays wrong)

    float* h = ybuf;                    // TT*DI, dead before scan writes ybuf

    embed_kernel<<<TT, DI / 4, 0, stream>>>(ids, mask, emb, x);
    concat_w_kernel<<<dim3(NW, NL), 256, 0, stream>>>(sB_w, sC_w, sD1_w, Wcat);

    for (int l = 0; l < NL; ++l) {
        const float* Wi_l  = Wi    + (size_t)l * 2 * DM * DI;
        const float* cw_l  = conv_w + (size_t)l * DM * KC;
        const float* cb_l  = conv_b + (size_t)l * DM;
        const float* W2_l  = sD2_w + (size_t)l * DM * DD;
        const float* A_l   = Amat  + (size_t)l * DM * DS;
        const float* Dp_l  = Dp    + (size_t)l * DM;
        const float* Wo_l  = out_w + (size_t)l * DI * DM;
        const float* nw_l  = norm_w + (size_t)l * DI;
        const float* Wcat_l = Wcat + (size_t)l * NW * DM;

        rmsnorm_kernel<<<TT, 256, 0, stream>>>(x, nw_l, h);

        // proj = h @ Wi^T : M=TT, N=2*DM, K=DI
        gemm_nt_f32<<<dim3(2 * DM / 128, TT / 128), 256, 0, stream>>>(
            h, Wi_l, nullptr, nullptr, proj, TT, 2 * DM, DI, DI, DI, 2 * DM, 0);

        conv_silu_kernel<<<dim3(TT, DM / 256), 256, 0, stream>>>(proj, cw_l, cb_l, aconv);

        // BCD = aconv @ Wcat^T (Bm | Cm | dd1)
        gemm_skinny<<<TT / 32, 256, 0, stream>>>(aconv, Wcat_l, BCD);

        // delta = softplus(Dp + dd1 @ W2^T) : M=TT, N=DM, K=DD ; dd1 = BCD cols 32..127
        gemm_nt_f32<<<dim3(DM / 128, TT / 128), 256, 0, stream>>>(
            BCD + 32, W2_l, nullptr, Dp_l, delta, TT, DM, DD, NW, DD, DM, 1);

        // chunk-parallel scan
        scan_pass1<<<dim3(DM / 16, NCH, BB), 256, 0, stream>>>(
            delta, aconv, BCD, A_l, PQ);
        scan_carry<<<BB * DM * DS / 256, 256, 0, stream>>>(PQ);
        scan_pass2<<<dim3(DM / 16, NCH, BB), 256, 0, stream>>>(
            delta, aconv, BCD, proj, A_l, Dp_l, PQ, ybuf);

        // x = x + y @ Wo^T : M=TT, N=DI, K=DM
        gemm_nt_f32<<<dim3(DI / 128, TT / 128), 256, 0, stream>>>(
            ybuf, Wo_l, x, nullptr, x, TT, DI, DM, DM, DM, DI, 0);
    }

    cls_kernel<<<TT, 64, 0, stream>>>(x, cls_w, cls_b, logits);
}

// Round 4
// 1025.428 us; speedup vs baseline: 4.7094x; 1.6237x over previous
//
#include <hip/hip_runtime.h>
#include <hip/hip_bf16.h>
#include <math.h>

// Problem constants
#define NLAB 9
#define NL   2
#define DI   768
#define DM   1536
#define DS   16
#define KC   4
#define DD   96
#define BB   2
#define SS   2048
#define TT   (BB*SS)
#define EPSF 1e-6f

// chunked scan config
#define NCH  32
#define CL   (SS/NCH)   // 64

// skinny fused projection width: 16 (B) + 16 (C) + 96 (dd1)
#define NW   128

typedef __attribute__((ext_vector_type(4))) float f32x4;
typedef __attribute__((ext_vector_type(8))) short bf16x8;

__device__ __forceinline__ float siluf(float x) { return x / (1.f + __expf(-x)); }
__device__ __forceinline__ float softplusf(float x) { return x > 15.f ? x : log1pf(__expf(x)); }

// f32 -> bf16 (RNE, finite inputs)
__device__ __forceinline__ unsigned short f2bf(float f) {
    unsigned u = __float_as_uint(f);
    return (unsigned short)((u + 0x7fffu + ((u >> 16) & 1u)) >> 16);
}

__global__ void f32_to_bf16_kernel(const float* __restrict__ src,
                                   unsigned short* __restrict__ dst, int n)
{
    int i = (blockIdx.x * 256 + threadIdx.x) * 8;
    if (i >= n) return;
    float4 a = *(const float4*)(src + i);
    float4 b = *(const float4*)(src + i + 4);
    unsigned short o[8] = {f2bf(a.x), f2bf(a.y), f2bf(a.z), f2bf(a.w),
                           f2bf(b.x), f2bf(b.y), f2bf(b.z), f2bf(b.w)};
    *(ulonglong2*)0; // unreachable pattern guard removed below
}

// (replaced above stub with real body via overload-free second definition is not allowed;
//  actual implementation:)
__global__ void f32_to_bf16(const float* __restrict__ src,
                            unsigned short* __restrict__ dst, int n)
{
    int i = (blockIdx.x * 256 + threadIdx.x) * 8;
    if (i >= n) return;
    float4 a = *(const float4*)(src + i);
    float4 b = *(const float4*)(src + i + 4);
    union { unsigned short s[8]; uint4 v; } o;
    o.s[0] = f2bf(a.x); o.s[1] = f2bf(a.y); o.s[2] = f2bf(a.z); o.s[3] = f2bf(a.w);
    o.s[4] = f2bf(b.x); o.s[5] = f2bf(b.y); o.s[6] = f2bf(b.z); o.s[7] = f2bf(b.w);
    *(uint4*)(dst + i) = o.v;
}

// x[t,:] = emb[ids[t],:] * mask[t]
__global__ void embed_kernel(const int* __restrict__ ids, const int* __restrict__ mask,
                             const float* __restrict__ emb, float* __restrict__ x)
{
    int t = blockIdx.x;
    int i = threadIdx.x;
    float m = (float)mask[t];
    int id = ids[t];
    float4 v = ((const float4*)(emb + (size_t)id * DI))[i];
    v.x *= m; v.y *= m; v.z *= m; v.w *= m;
    ((float4*)(x + (size_t)t * DI))[i] = v;
}

// h16[t,:] = bf16( x[t,:] * rsqrt(mean(x^2)+eps) * w )
__global__ void rmsnorm_kernel(const float* __restrict__ x, const float* __restrict__ w,
                               unsigned short* __restrict__ h)
{
    __shared__ float red[4];
    int t = blockIdx.x;
    const float* xr = x + (size_t)t * DI;
    float ss = 0.f;
    for (int i = threadIdx.x; i < DI; i += 256) { float v = xr[i]; ss += v * v; }
    #pragma unroll
    for (int m = 1; m < 64; m <<= 1) ss += __shfl_xor(ss, m, 64);
    if ((threadIdx.x & 63) == 0) red[threadIdx.x >> 6] = ss;
    __syncthreads();
    float scale = rsqrtf((red[0] + red[1] + red[2] + red[3]) * (1.f / DI) + EPSF);
    for (int i = threadIdx.x; i < DI; i += 256)
        h[(size_t)t * DI + i] = f2bf(xr[i] * scale * w[i]);
}

// ---- bf16 MFMA GEMM (m97 structure) ----
// C[m,n] = act(A[m,:]·B[n,:] + bias[n]) + Rres[m,n];  A:[M,K] bf16, B:[N,K] bf16 (NT)
// BM=BN=128, BK=32, 256 thr = 4 waves (2x2 of 64x64), 16x16x32 MFMA, 4x4 frags/wave.
// REQUIRES M%128==0, N%128==0, K%32==0, rows 16B-aligned.
__global__ __launch_bounds__(256) void gemm_bf16(
    const unsigned short* __restrict__ A, const unsigned short* __restrict__ B,
    const float* __restrict__ Rres, const float* __restrict__ bias,
    float* __restrict__ C, int M, int N, int K,
    int lda, int ldb, int ldc, int act)
{
    __shared__ unsigned short As[128 * 32];
    __shared__ unsigned short Bs[128 * 32];
    const int tid = threadIdx.x;
    const int wave = tid >> 6, lane = tid & 63;
    const int bm = blockIdx.y * 128, bn = blockIdx.x * 128;
    const int wm = (wave >> 1) * 64, wn = (wave & 1) * 64;
    const int lr = lane & 15, kh = lane >> 4;

    f32x4 acc[4][4] = {};

    const unsigned short* Arow = A + (size_t)bm * lda;
    const unsigned short* Brow = B + (size_t)bn * ldb;

    for (int kt = 0; kt < K; kt += 32) {
        // stage 128x32 bf16 tiles via global_load_lds width=16
        #pragma unroll
        for (int it = 0; it < 2; ++it) {
            int rbase = it * 64 + wave * 16;
            int row = rbase + (lane >> 2);
            int c8 = (lane & 3) * 8;
            __builtin_amdgcn_global_load_lds(
                (const __attribute__((address_space(1))) unsigned int*)(Arow + (size_t)row * lda + kt + c8),
                (__attribute__((address_space(3))) unsigned int*)(As + rbase * 32),
                16, 0, 0);
            __builtin_amdgcn_global_load_lds(
                (const __attribute__((address_space(1))) unsigned int*)(Brow + (size_t)row * ldb + kt + c8),
                (__attribute__((address_space(3))) unsigned int*)(Bs + rbase * 32),
                16, 0, 0);
        }
        __syncthreads();   // drains vmcnt -> LDS visible

        bf16x8 af[4], bfr[4];
        #pragma unroll
        for (int i = 0; i < 4; ++i)
            af[i] = *(const bf16x8*)&As[(wm + i * 16 + lr) * 32 + kh * 8];
        #pragma unroll
        for (int j = 0; j < 4; ++j)
            bfr[j] = *(const bf16x8*)&Bs[(wn + j * 16 + lr) * 32 + kh * 8];
        #pragma unroll
        for (int i = 0; i < 4; ++i)
            #pragma unroll
            for (int j = 0; j < 4; ++j)
                acc[i][j] = __builtin_amdgcn_mfma_f32_16x16x32_bf16(af[i], bfr[j], acc[i][j], 0, 0, 0);
        __syncthreads();   // all reads done before restage
    }

    // C/D layout: col = lane&15, row = (lane>>4)*4 + reg
    #pragma unroll
    for (int i = 0; i < 4; ++i) {
        #pragma unroll
        for (int j = 0; j < 4; ++j) {
            #pragma unroll
            for (int r = 0; r < 4; ++r) {
                int row = bm + wm + i * 16 + kh * 4 + r;
                int col = bn + wn + j * 16 + lr;
                float v = acc[i][j][r];
                if (bias) v += bias[col];
                if (act == 1) v = softplusf(v);
                if (Rres) v += Rres[(size_t)row * ldc + col];
                C[(size_t)row * ldc + col] = v;
            }
        }
    }
}

// f32 NT GEMM (kept for delta: K=96). 128x128 tile, BK=16, 8x8/thread.
__global__ __launch_bounds__(256) void gemm_nt_f32(
    const float* __restrict__ Amat, const float* __restrict__ Bmat,
    const float* __restrict__ Rres, const float* __restrict__ bias,
    float* __restrict__ C, int M, int N, int Kd,
    int lda, int ldb, int ldc, int act)
{
    constexpr int BM = 128, BN = 128, BK = 16;
    __shared__ float As[BK][BM + 4];
    __shared__ float Bs[BK][BN + 4];
    const int tid = threadIdx.x;
    const int bm = blockIdx.y * BM;
    const int bn = blockIdx.x * BN;
    const int ty = tid >> 4, tx = tid & 15;
    float acc[8][8] = {};

    for (int kt = 0; kt < Kd; kt += BK) {
        #pragma unroll
        for (int sidx = 0; sidx < 2; ++sidx) {
            int slot = tid + sidx * 256;
            int row = slot >> 2;
            int kc = (slot & 3) << 2;
            float4 va = *(const float4*)(Amat + (size_t)(bm + row) * lda + kt + kc);
            As[kc + 0][row] = va.x; As[kc + 1][row] = va.y;
            As[kc + 2][row] = va.z; As[kc + 3][row] = va.w;
            float4 vb = *(const float4*)(Bmat + (size_t)(bn + row) * ldb + kt + kc);
            Bs[kc + 0][row] = vb.x; Bs[kc + 1][row] = vb.y;
            Bs[kc + 2][row] = vb.z; Bs[kc + 3][row] = vb.w;
        }
        __syncthreads();
        #pragma unroll
        for (int kk = 0; kk < BK; ++kk) {
            float a[8], b[8];
            *(float4*)&a[0] = *(const float4*)&As[kk][ty * 8];
            *(float4*)&a[4] = *(const float4*)&As[kk][ty * 8 + 4];
            *(float4*)&b[0] = *(const float4*)&Bs[kk][tx * 8];
            *(float4*)&b[4] = *(const float4*)&Bs[kk][tx * 8 + 4];
            #pragma unroll
            for (int i = 0; i < 8; ++i)
                #pragma unroll
                for (int j = 0; j < 8; ++j)
                    acc[i][j] += a[i] * b[j];
        }
        __syncthreads();
    }
    #pragma unroll
    for (int i = 0; i < 8; ++i) {
        int m = bm + ty * 8 + i;
        #pragma unroll
        for (int j = 0; j < 8; ++j) {
            int n = bn + tx * 8 + j;
            float v = acc[i][j];
            if (bias) v += bias[n];
            if (act == 1) v = softplusf(v);
            if (Rres) v += Rres[(size_t)m * ldc + n];
            C[(size_t)m * ldc + n] = v;
        }
    }
}

// causal depthwise conv (K=4) + silu
__global__ void conv_silu_kernel(const float* __restrict__ proj, const float* __restrict__ cw,
                                 const float* __restrict__ cb, float* __restrict__ aconv)
{
    int t = blockIdx.x;
    int d = blockIdx.y * 256 + threadIdx.x;
    int p = t & (SS - 1);
    float acc = cb[d];
    #pragma unroll
    for (int j = 0; j < KC; ++j) {
        int pp = p - (KC - 1) + j;
        if (pp >= 0)
            acc += cw[d * KC + j] * proj[(size_t)(t - (KC - 1) + j) * (2 * DM) + d];
    }
    aconv[(size_t)t * DM + d] = siluf(acc);
}

// pack [WB;WC;W1] -> Wcat[l][128][DM]
__global__ void concat_w_kernel(const float* __restrict__ WB, const float* __restrict__ WC,
                                const float* __restrict__ W1, float* __restrict__ Wcat)
{
    int l = blockIdx.y;
    int row = blockIdx.x;
    const float* src;
    if (row < 16)      src = WB + (size_t)l * DS * DM + (size_t)row * DM;
    else if (row < 32) src = WC + (size_t)l * DS * DM + (size_t)(row - 16) * DM;
    else               src = W1 + (size_t)l * DD * DM + (size_t)(row - 32) * DM;
    float* dst = Wcat + ((size_t)l * NW + row) * DM;
    for (int i = threadIdx.x; i < DM / 4; i += 256)
        ((float4*)dst)[i] = ((const float4*)src)[i];
}

// BCD = aconv @ Wcat^T : M=TT, N=128, K=DM. BM=32,BN=128,BK=32, 4x4/thread.
__global__ __launch_bounds__(256) void gemm_skinny(
    const float* __restrict__ Amat, const float* __restrict__ Bmat,
    float* __restrict__ C)
{
    constexpr int BM = 32, BN = 128, BK = 32;
    __shared__ float As[BK][BM + 4];
    __shared__ float Bs[BK][BN + 4];
    const int tid = threadIdx.x;
    const int bm = blockIdx.x * BM;
    const int ty = tid >> 5, tx = tid & 31;
    float acc[4][4] = {};

    for (int kt = 0; kt < DM; kt += BK) {
        {
            int row = tid >> 3, kc = (tid & 7) << 2;
            float4 va = *(const float4*)(Amat + (size_t)(bm + row) * DM + kt + kc);
            As[kc + 0][row] = va.x; As[kc + 1][row] = va.y;
            As[kc + 2][row] = va.z; As[kc + 3][row] = va.w;
        }
        #pragma unroll
        for (int sidx = 0; sidx < 4; ++sidx) {
            int slot = tid + sidx * 256;
            int row = slot >> 3, kc = (slot & 7) << 2;
            float4 vb = *(const float4*)(Bmat + (size_t)row * DM + kt + kc);
            Bs[kc + 0][row] = vb.x; Bs[kc + 1][row] = vb.y;
            Bs[kc + 2][row] = vb.z; Bs[kc + 3][row] = vb.w;
        }
        __syncthreads();
        #pragma unroll
        for (int kk = 0; kk < BK; ++kk) {
            float4 a = *(const float4*)&As[kk][ty * 4];
            float4 b = *(const float4*)&Bs[kk][tx * 4];
            float av[4] = {a.x, a.y, a.z, a.w};
            float bv[4] = {b.x, b.y, b.z, b.w};
            #pragma unroll
            for (int i = 0; i < 4; ++i)
                #pragma unroll
                for (int j = 0; j < 4; ++j)
                    acc[i][j] += av[i] * bv[j];
        }
        __syncthreads();
    }
    #pragma unroll
    for (int i = 0; i < 4; ++i) {
        float4 v = make_float4(acc[i][0], acc[i][1], acc[i][2], acc[i][3]);
        *(float4*)(C + (size_t)(bm + ty * 4 + i) * NW + tx * 4) = v;
    }
}

// ---- chunk-parallel selective scan ----
__global__ __launch_bounds__(256) void scan_pass1(
    const float* __restrict__ delta, const float* __restrict__ aconv,
    const float* __restrict__ BCD, const float* __restrict__ Amat,
    float2* __restrict__ PQ)
{
    __shared__ float sd[CL][16], sa[CL][16], sb[CL][16];
    int b = blockIdx.z, c = blockIdx.y;
    int d0 = blockIdx.x * 16;
    int tid = threadIdx.x;
    int dl = tid >> 4, s = tid & 15;
    size_t rowbase = (size_t)b * SS + (size_t)c * CL;

    for (int i = tid; i < CL * 16; i += 256) {
        int tt = i >> 4, dc = i & 15;
        sd[tt][dc] = delta[(rowbase + tt) * DM + d0 + dc];
        sa[tt][dc] = aconv[(rowbase + tt) * DM + d0 + dc];
        ((float*)sb)[i] = BCD[(rowbase + tt) * NW + dc];
    }
    __syncthreads();

    int d = d0 + dl;
    float negA = -Amat[(size_t)d * DS + s];
    float P = 1.f, hid = 0.f;
    for (int t = 0; t < CL; ++t) {
        float dt = sd[t][dl];
        float av = sa[t][dl];
        float Abar = __expf(dt * negA);
        hid = Abar * hid + (dt * av) * sb[t][s];
        P *= Abar;
    }
    PQ[((size_t)(b * NCH + c) * DM + d) * DS + s] = make_float2(P, hid);
}

__global__ void scan_carry(float2* __restrict__ PQ)
{
    int idx = blockIdx.x * 256 + threadIdx.x;
    int b = idx / (DM * DS);
    int r = idx - b * (DM * DS);
    float carry = 0.f;
    for (int c = 0; c < NCH; ++c) {
        size_t o = (size_t)(b * NCH + c) * (DM * DS) + r;
        float2 pq = PQ[o];
        PQ[o].x = carry;
        carry = pq.x * carry + pq.y;
    }
}

__global__ __launch_bounds__(256) void scan_pass2(
    const float* __restrict__ delta, const float* __restrict__ aconv,
    const float* __restrict__ BCD,
    const float* __restrict__ proj, const float* __restrict__ Amat,
    const float* __restrict__ Dp, const float2* __restrict__ PQ,
    unsigned short* __restrict__ y)
{
    __shared__ float sd[CL][16], sa[CL][16], sb[CL][16], sc[CL][16], sg[CL][16], sy[CL][16];
    int b = blockIdx.z, c = blockIdx.y;
    int d0 = blockIdx.x * 16;
    int tid = threadIdx.x;
    int dl = tid >> 4, s = tid & 15;
    size_t rowbase = (size_t)b * SS + (size_t)c * CL;

    for (int i = tid; i < CL * 16; i += 256) {
        int tt = i >> 4, dc = i & 15;
        size_t row = rowbase + tt;
        sd[tt][dc] = delta[row * DM + d0 + dc];
        sa[tt][dc] = aconv[row * DM + d0 + dc];
        sg[tt][dc] = proj[row * (2 * DM) + DM + d0 + dc];
        ((float*)sb)[i] = BCD[row * NW + dc];
        ((float*)sc)[i] = BCD[row * NW + 16 + dc];
    }
    __syncthreads();

    int d = d0 + dl;
    float negA = -Amat[(size_t)d * DS + s];
    float Dpd = Dp[d];
    float hid = PQ[((size_t)(b * NCH + c) * DM + d) * DS + s].x;
    for (int t = 0; t < CL; ++t) {
        float dt = sd[t][dl];
        float av = sa[t][dl];
        float Abar = __expf(dt * negA);
        hid = Abar * hid + (dt * av) * sb[t][s];
        float contrib = hid * sc[t][s];
        #pragma unroll
        for (int m = 1; m < 16; m <<= 1) contrib += __shfl_xor(contrib, m, 64);
        if (s == 0)
            sy[t][dl] = (contrib + Dpd * av) * siluf(sg[t][dl]);
    }
    __syncthreads();
    for (int i = tid; i < CL * 16; i += 256)
        y[(rowbase + (i >> 4)) * DM + d0 + (i & 15)] = f2bf(((float*)sy)[i]);
}

// logits
__global__ void cls_kernel(const float* __restrict__ x, const float* __restrict__ W,
                           const float* __restrict__ bias, float* __restrict__ out)
{
    int t = blockIdx.x;
    int lane = threadIdx.x;
    const float* xr = x + (size_t)t * DI;
    float acc[NLAB];
    #pragma unroll
    for (int n = 0; n < NLAB; ++n) acc[n] = 0.f;
    for (int i = lane; i < DI; i += 64) {
        float xv = xr[i];
        #pragma unroll
        for (int n = 0; n < NLAB; ++n) acc[n] += xv * W[(size_t)n * DI + i];
    }
    #pragma unroll
    for (int n = 0; n < NLAB; ++n)
        #pragma unroll
        for (int m = 1; m < 64; m <<= 1) acc[n] += __shfl_xor(acc[n], m, 64);
    if (lane < NLAB) out[(size_t)t * NLAB + lane] = acc[lane] + bias[lane];
}

extern "C" void kernel_launch(void* const* d_in, const int* in_sizes, int n_in,
                              void* d_out, int out_size, void* d_ws, size_t ws_size,
                              hipStream_t stream)
{
    const int*   ids    = (const int*)d_in[0];
    const int*   mask   = (const int*)d_in[1];
    const float* emb    = (const float*)d_in[2];
    const float* norm_w = (const float*)d_in[3];
    const float* Wi     = (const float*)d_in[4];
    const float* conv_w = (const float*)d_in[5];
    const float* conv_b = (const float*)d_in[6];
    const float* sB_w   = (const float*)d_in[7];
    const float* sC_w   = (const float*)d_in[8];
    const float* sD1_w  = (const float*)d_in[9];
    const float* sD2_w  = (const float*)d_in[10];
    const float* Amat   = (const float*)d_in[11];
    const float* Dp     = (const float*)d_in[12];
    const float* out_w  = (const float*)d_in[13];
    const float* cls_w  = (const float*)d_in[14];
    const float* cls_b  = (const float*)d_in[15];
    float* logits = (float*)d_out;

    // workspace layout (float units)
    float* ws = (float*)d_ws;
    size_t off = 0;
    float* x     = ws + off; off += (size_t)TT * DI;
    float* proj  = ws + off; off += (size_t)TT * 2 * DM;
    float* aconv = ws + off; off += (size_t)TT * DM;
    float* delta = ws + off; off += (size_t)TT * DM;      // h16 overlays (liveness disjoint)
    float* BCD   = ws + off; off += (size_t)TT * NW;
    float* Wcat  = ws + off; off += (size_t)NL * NW * DM;
    float2* PQ   = (float2*)(ws + off); off += (size_t)BB * NCH * DM * DS * 2;
    unsigned short* y16  = (unsigned short*)(ws + off); off += (size_t)TT * DM / 2;
    unsigned short* Wi16 = (unsigned short*)(ws + off); off += (size_t)2 * DM * DI / 2;
    unsigned short* Wo16 = (unsigned short*)(ws + off); off += (size_t)DI * DM / 2;
    if (ws_size < off * sizeof(float)) return;  // fail loud

    unsigned short* h16 = (unsigned short*)delta;   // TT*DI bf16, dead before delta written

    embed_kernel<<<TT, DI / 4, 0, stream>>>(ids, mask, emb, x);
    concat_w_kernel<<<dim3(NW, NL), 256, 0, stream>>>(sB_w, sC_w, sD1_w, Wcat);

    for (int l = 0; l < NL; ++l) {
        const float* Wi_l  = Wi    + (size_t)l * 2 * DM * DI;
        const float* cw_l  = conv_w + (size_t)l * DM * KC;
        const float* cb_l  = conv_b + (size_t)l * DM;
        const float* W2_l  = sD2_w + (size_t)l * DM * DD;
        const float* A_l   = Amat  + (size_t)l * DM * DS;
        const float* Dp_l  = Dp    + (size_t)l * DM;
        const float* Wo_l  = out_w + (size_t)l * DI * DM;
        const float* nw_l  = norm_w + (size_t)l * DI;
        const float* Wcat_l = Wcat + (size_t)l * NW * DM;

        // weight conversions for this layer
        f32_to_bf16<<<(2 * DM * DI / 8 + 255) / 256, 256, 0, stream>>>(Wi_l, Wi16, 2 * DM * DI);
        f32_to_bf16<<<(DI * DM / 8 + 255) / 256, 256, 0, stream>>>(Wo_l, Wo16, DI * DM);

        rmsnorm_kernel<<<TT, 256, 0, stream>>>(x, nw_l, h16);

        // proj = h @ Wi^T : M=TT, N=2*DM, K=DI  (bf16 MFMA)
        gemm_bf16<<<dim3(2 * DM / 128, TT / 128), 256, 0, stream>>>(
            h16, Wi16, nullptr, nullptr, proj, TT, 2 * DM, DI, DI, DI, 2 * DM, 0);

        conv_silu_kernel<<<dim3(TT, DM / 256), 256, 0, stream>>>(proj, cw_l, cb_l, aconv);

        // BCD = aconv @ Wcat^T (Bm | Cm | dd1)
        gemm_skinny<<<TT / 32, 256, 0, stream>>>(aconv, Wcat_l, BCD);

        // delta = softplus(Dp + dd1 @ W2^T) : K=96 (f32)
        gemm_nt_f32<<<dim3(DM / 128, TT / 128), 256, 0, stream>>>(
            BCD + 32, W2_l, nullptr, Dp_l, delta, TT, DM, DD, NW, DD, DM, 1);

        // chunk-parallel scan
        scan_pass1<<<dim3(DM / 16, NCH, BB), 256, 0, stream>>>(
            delta, aconv, BCD, A_l, PQ);
        scan_carry<<<BB * DM * DS / 256, 256, 0, stream>>>(PQ);
        scan_pass2<<<dim3(DM / 16, NCH, BB), 256, 0, stream>>>(
            delta, aconv, BCD, proj, A_l, Dp_l, PQ, y16);

        // x = x + y @ Wo^T : M=TT, N=DI, K=DM  (bf16 MFMA)
        gemm_bf16<<<dim3(DI / 128, TT / 128), 256, 0, stream>>>(
            y16, Wo16, x, nullptr, x, TT, DI, DM, DM, DM, DI, 0);
    }

    cls_kernel<<<TT, 64, 0, stream>>>(x, cls_w, cls_b, logits);
}

// Round 6
// 977.941 us; speedup vs baseline: 4.9381x; 1.0486x over previous
//
#include <hip/hip_runtime.h>
#include <hip/hip_bf16.h>
#include <math.h>

// Problem constants
#define NLAB 9
#define NL   2
#define DI   768
#define DM   1536
#define DS   16
#define KC   4
#define DD   96
#define BB   2
#define SS   2048
#define TT   (BB*SS)
#define EPSF 1e-6f

// chunked scan config
#define NCH  32
#define CL   (SS/NCH)   // 64

// skinny fused projection width: 16 (B) + 16 (C) + 96 (dd1)
#define NW   128

typedef __attribute__((ext_vector_type(4))) float f32x4;
typedef __attribute__((ext_vector_type(8))) short bf16x8;
typedef __attribute__((ext_vector_type(4))) unsigned short us4;

__device__ __forceinline__ float siluf(float x) { return x / (1.f + __expf(-x)); }
__device__ __forceinline__ float softplusf(float x) { return x > 15.f ? x : log1pf(__expf(x)); }

// f32 -> bf16 (RNE, finite inputs)
__device__ __forceinline__ unsigned short f2bf(float f) {
    unsigned u = __float_as_uint(f);
    return (unsigned short)((u + 0x7fffu + ((u >> 16) & 1u)) >> 16);
}

__global__ void f32_to_bf16(const float* __restrict__ src,
                            unsigned short* __restrict__ dst, int n)
{
    int i = (blockIdx.x * 256 + threadIdx.x) * 8;
    if (i >= n) return;
    float4 a = *(const float4*)(src + i);
    float4 b = *(const float4*)(src + i + 4);
    union { unsigned short s[8]; uint4 v; } o;
    o.s[0] = f2bf(a.x); o.s[1] = f2bf(a.y); o.s[2] = f2bf(a.z); o.s[3] = f2bf(a.w);
    o.s[4] = f2bf(b.x); o.s[5] = f2bf(b.y); o.s[6] = f2bf(b.z); o.s[7] = f2bf(b.w);
    *(uint4*)(dst + i) = o.v;
}

// x[t,:] = emb[ids[t],:] * mask[t]
__global__ void embed_kernel(const int* __restrict__ ids, const int* __restrict__ mask,
                             const float* __restrict__ emb, float* __restrict__ x)
{
    int t = blockIdx.x;
    int i = threadIdx.x;
    float m = (float)mask[t];
    int id = ids[t];
    float4 v = ((const float4*)(emb + (size_t)id * DI))[i];
    v.x *= m; v.y *= m; v.z *= m; v.w *= m;
    ((float4*)(x + (size_t)t * DI))[i] = v;
}

// h16[t,:] = bf16( x[t,:] * rsqrt(mean(x^2)+eps) * w )
__global__ void rmsnorm_kernel(const float* __restrict__ x, const float* __restrict__ w,
                               unsigned short* __restrict__ h)
{
    __shared__ float red[4];
    int t = blockIdx.x;
    const float* xr = x + (size_t)t * DI;
    float ss = 0.f;
    for (int i = threadIdx.x; i < DI; i += 256) { float v = xr[i]; ss += v * v; }
    #pragma unroll
    for (int m = 1; m < 64; m <<= 1) ss += __shfl_xor(ss, m, 64);
    if ((threadIdx.x & 63) == 0) red[threadIdx.x >> 6] = ss;
    __syncthreads();
    float scale = rsqrtf((red[0] + red[1] + red[2] + red[3]) * (1.f / DI) + EPSF);
    for (int i = threadIdx.x; i < DI; i += 256)
        h[(size_t)t * DI + i] = f2bf(xr[i] * scale * w[i]);
}

// ---- bf16 MFMA GEMM (m97 structure; replay-proven in R3) ----
// C[m,n] = act(A[m,:]·B[n,:] + bias[n]) + Rres[m,n];  A:[M,K] bf16, B:[N,K] bf16 (NT)
// REQUIRES M%128==0, N%128==0, K%32==0, rows 16B-aligned.
__global__ __launch_bounds__(256) void gemm_bf16(
    const unsigned short* __restrict__ A, const unsigned short* __restrict__ B,
    const float* __restrict__ Rres, const float* __restrict__ bias,
    float* __restrict__ C, int M, int N, int K,
    int lda, int ldb, int ldc, int act)
{
    __shared__ unsigned short As[128 * 32];
    __shared__ unsigned short Bs[128 * 32];
    const int tid = threadIdx.x;
    const int wave = tid >> 6, lane = tid & 63;
    const int bm = blockIdx.y * 128, bn = blockIdx.x * 128;
    const int wm = (wave >> 1) * 64, wn = (wave & 1) * 64;
    const int lr = lane & 15, kh = lane >> 4;

    f32x4 acc[4][4] = {};

    const unsigned short* Arow = A + (size_t)bm * lda;
    const unsigned short* Brow = B + (size_t)bn * ldb;

    for (int kt = 0; kt < K; kt += 32) {
        #pragma unroll
        for (int it = 0; it < 2; ++it) {
            int rbase = it * 64 + wave * 16;
            int row = rbase + (lane >> 2);
            int c8 = (lane & 3) * 8;
            __builtin_amdgcn_global_load_lds(
                (const __attribute__((address_space(1))) unsigned int*)(Arow + (size_t)row * lda + kt + c8),
                (__attribute__((address_space(3))) unsigned int*)(As + rbase * 32),
                16, 0, 0);
            __builtin_amdgcn_global_load_lds(
                (const __attribute__((address_space(1))) unsigned int*)(Brow + (size_t)row * ldb + kt + c8),
                (__attribute__((address_space(3))) unsigned int*)(Bs + rbase * 32),
                16, 0, 0);
        }
        __syncthreads();

        bf16x8 af[4], bfr[4];
        #pragma unroll
        for (int i = 0; i < 4; ++i)
            af[i] = *(const bf16x8*)&As[(wm + i * 16 + lr) * 32 + kh * 8];
        #pragma unroll
        for (int j = 0; j < 4; ++j)
            bfr[j] = *(const bf16x8*)&Bs[(wn + j * 16 + lr) * 32 + kh * 8];
        #pragma unroll
        for (int i = 0; i < 4; ++i)
            #pragma unroll
            for (int j = 0; j < 4; ++j)
                acc[i][j] = __builtin_amdgcn_mfma_f32_16x16x32_bf16(af[i], bfr[j], acc[i][j], 0, 0, 0);
        __syncthreads();
    }

    #pragma unroll
    for (int i = 0; i < 4; ++i) {
        #pragma unroll
        for (int j = 0; j < 4; ++j) {
            #pragma unroll
            for (int r = 0; r < 4; ++r) {
                int row = bm + wm + i * 16 + kh * 4 + r;
                int col = bn + wn + j * 16 + lr;
                float v = acc[i][j][r];
                if (bias) v += bias[col];
                if (act == 1) v = softplusf(v);
                if (Rres) v += Rres[(size_t)row * ldc + col];
                C[(size_t)row * ldc + col] = v;
            }
        }
    }
}

// causal depthwise conv (K=4) + silu
__global__ void conv_silu_kernel(const float* __restrict__ proj, const float* __restrict__ cw,
                                 const float* __restrict__ cb, float* __restrict__ aconv)
{
    int t = blockIdx.x;
    int d = blockIdx.y * 256 + threadIdx.x;
    int p = t & (SS - 1);
    float acc = cb[d];
    #pragma unroll
    for (int j = 0; j < KC; ++j) {
        int pp = p - (KC - 1) + j;
        if (pp >= 0)
            acc += cw[d * KC + j] * proj[(size_t)(t - (KC - 1) + j) * (2 * DM) + d];
    }
    aconv[(size_t)t * DM + d] = siluf(acc);
}

// pack [WB;WC;W1] -> Wcat[l][128][DM]
__global__ void concat_w_kernel(const float* __restrict__ WB, const float* __restrict__ WC,
                                const float* __restrict__ W1, float* __restrict__ Wcat)
{
    int l = blockIdx.y;
    int row = blockIdx.x;
    const float* src;
    if (row < 16)      src = WB + (size_t)l * DS * DM + (size_t)row * DM;
    else if (row < 32) src = WC + (size_t)l * DS * DM + (size_t)(row - 16) * DM;
    else               src = W1 + (size_t)l * DD * DM + (size_t)(row - 32) * DM;
    float* dst = Wcat + ((size_t)l * NW + row) * DM;
    for (int i = threadIdx.x; i < DM / 4; i += 256)
        ((float4*)dst)[i] = ((const float4*)src)[i];
}

// BCD = aconv @ Wcat^T : M=TT, N=128, K=DM. Also emits dd1 (cols 32..127) as bf16.
__global__ __launch_bounds__(256) void gemm_skinny(
    const float* __restrict__ Amat, const float* __restrict__ Bmat,
    float* __restrict__ C, unsigned short* __restrict__ dd16)
{
    constexpr int BM = 32, BN = 128, BK = 32;
    __shared__ float As[BK][BM + 4];
    __shared__ float Bs[BK][BN + 4];
    const int tid = threadIdx.x;
    const int bm = blockIdx.x * BM;
    const int ty = tid >> 5, tx = tid & 31;
    float acc[4][4] = {};

    for (int kt = 0; kt < DM; kt += BK) {
        {
            int row = tid >> 3, kc = (tid & 7) << 2;
            float4 va = *(const float4*)(Amat + (size_t)(bm + row) * DM + kt + kc);
            As[kc + 0][row] = va.x; As[kc + 1][row] = va.y;
            As[kc + 2][row] = va.z; As[kc + 3][row] = va.w;
        }
        #pragma unroll
        for (int sidx = 0; sidx < 4; ++sidx) {
            int slot = tid + sidx * 256;
            int row = slot >> 3, kc = (slot & 7) << 2;
            float4 vb = *(const float4*)(Bmat + (size_t)row * DM + kt + kc);
            Bs[kc + 0][row] = vb.x; Bs[kc + 1][row] = vb.y;
            Bs[kc + 2][row] = vb.z; Bs[kc + 3][row] = vb.w;
        }
        __syncthreads();
        #pragma unroll
        for (int kk = 0; kk < BK; ++kk) {
            float4 a = *(const float4*)&As[kk][ty * 4];
            float4 b = *(const float4*)&Bs[kk][tx * 4];
            float av[4] = {a.x, a.y, a.z, a.w};
            float bv[4] = {b.x, b.y, b.z, b.w};
            #pragma unroll
            for (int i = 0; i < 4; ++i)
                #pragma unroll
                for (int j = 0; j < 4; ++j)
                    acc[i][j] += av[i] * bv[j];
        }
        __syncthreads();
    }
    #pragma unroll
    for (int i = 0; i < 4; ++i) {
        int row = bm + ty * 4 + i;
        float4 v = make_float4(acc[i][0], acc[i][1], acc[i][2], acc[i][3]);
        *(float4*)(C + (size_t)row * NW + tx * 4) = v;
        if (tx >= 8) {   // dd1 columns (32..127) -> bf16 copy for the delta MFMA GEMM
            us4 u = { f2bf(v.x), f2bf(v.y), f2bf(v.z), f2bf(v.w) };
            *(us4*)(dd16 + (size_t)row * DD + tx * 4 - 32) = u;
        }
    }
}

// ---- chunk-parallel selective scan (R3 replay-proven versions) ----
// PQ layout: [(b*NCH + c)*DM + d]*DS + s  as float2 {P, Q}; carry pass rewrites .x = carry-in
__global__ __launch_bounds__(256) void scan_pass1(
    const float* __restrict__ delta, const float* __restrict__ aconv,
    const float* __restrict__ BCD, const float* __restrict__ Amat,
    float2* __restrict__ PQ)
{
    __shared__ float sd[CL][16], sa[CL][16], sb[CL][16];
    int b = blockIdx.z, c = blockIdx.y;
    int d0 = blockIdx.x * 16;
    int tid = threadIdx.x;
    int dl = tid >> 4, s = tid & 15;
    size_t rowbase = (size_t)b * SS + (size_t)c * CL;

    for (int i = tid; i < CL * 16; i += 256) {
        int tt = i >> 4, dc = i & 15;
        sd[tt][dc] = delta[(rowbase + tt) * DM + d0 + dc];
        sa[tt][dc] = aconv[(rowbase + tt) * DM + d0 + dc];
        ((float*)sb)[i] = BCD[(rowbase + tt) * NW + dc];       // Bm = cols 0..15
    }
    __syncthreads();

    int d = d0 + dl;
    float negA = -Amat[(size_t)d * DS + s];
    float P = 1.f, hid = 0.f;
    for (int t = 0; t < CL; ++t) {
        float dt = sd[t][dl];
        float av = sa[t][dl];
        float Abar = __expf(dt * negA);
        hid = Abar * hid + (dt * av) * sb[t][s];
        P *= Abar;
    }
    PQ[((size_t)(b * NCH + c) * DM + d) * DS + s] = make_float2(P, hid);
}

// 49152 chains, NCH sequential chunk steps each; rewrites .x = carry-in
__global__ void scan_carry(float2* __restrict__ PQ)
{
    int idx = blockIdx.x * 256 + threadIdx.x;
    int b = idx / (DM * DS);
    int r = idx - b * (DM * DS);
    float carry = 0.f;
    for (int c = 0; c < NCH; ++c) {
        size_t o = (size_t)(b * NCH + c) * (DM * DS) + r;
        float2 pq = PQ[o];
        PQ[o].x = carry;
        carry = pq.x * carry + pq.y;
    }
}

__global__ __launch_bounds__(256) void scan_pass2(
    const float* __restrict__ delta, const float* __restrict__ aconv,
    const float* __restrict__ BCD,
    const float* __restrict__ proj, const float* __restrict__ Amat,
    const float* __restrict__ Dp, const float2* __restrict__ PQ,
    unsigned short* __restrict__ y)
{
    __shared__ float sd[CL][16], sa[CL][16], sb[CL][16], sc[CL][16], sg[CL][16], sy[CL][16];
    int b = blockIdx.z, c = blockIdx.y;
    int d0 = blockIdx.x * 16;
    int tid = threadIdx.x;
    int dl = tid >> 4, s = tid & 15;
    size_t rowbase = (size_t)b * SS + (size_t)c * CL;

    for (int i = tid; i < CL * 16; i += 256) {
        int tt = i >> 4, dc = i & 15;
        size_t row = rowbase + tt;
        sd[tt][dc] = delta[row * DM + d0 + dc];
        sa[tt][dc] = aconv[row * DM + d0 + dc];
        sg[tt][dc] = proj[row * (2 * DM) + DM + d0 + dc];
        ((float*)sb)[i] = BCD[row * NW + dc];          // Bm
        ((float*)sc)[i] = BCD[row * NW + 16 + dc];     // Cm
    }
    __syncthreads();

    int d = d0 + dl;
    float negA = -Amat[(size_t)d * DS + s];
    float Dpd = Dp[d];
    float hid = PQ[((size_t)(b * NCH + c) * DM + d) * DS + s].x;  // carry-in
    for (int t = 0; t < CL; ++t) {
        float dt = sd[t][dl];
        float av = sa[t][dl];
        float Abar = __expf(dt * negA);
        hid = Abar * hid + (dt * av) * sb[t][s];
        float contrib = hid * sc[t][s];
        #pragma unroll
        for (int m = 1; m < 16; m <<= 1) contrib += __shfl_xor(contrib, m, 64);
        if (s == 0)
            sy[t][dl] = (contrib + Dpd * av) * siluf(sg[t][dl]);
    }
    __syncthreads();
    for (int i = tid; i < CL * 16; i += 256)
        y[(rowbase + (i >> 4)) * DM + d0 + (i & 15)] = f2bf(((float*)sy)[i]);
}

// logits
__global__ void cls_kernel(const float* __restrict__ x, const float* __restrict__ W,
                           const float* __restrict__ bias, float* __restrict__ out)
{
    int t = blockIdx.x;
    int lane = threadIdx.x;
    const float* xr = x + (size_t)t * DI;
    float acc[NLAB];
    #pragma unroll
    for (int n = 0; n < NLAB; ++n) acc[n] = 0.f;
    for (int i = lane; i < DI; i += 64) {
        float xv = xr[i];
        #pragma unroll
        for (int n = 0; n < NLAB; ++n) acc[n] += xv * W[(size_t)n * DI + i];
    }
    #pragma unroll
    for (int n = 0; n < NLAB; ++n)
        #pragma unroll
        for (int m = 1; m < 64; m <<= 1) acc[n] += __shfl_xor(acc[n], m, 64);
    if (lane < NLAB) out[(size_t)t * NLAB + lane] = acc[lane] + bias[lane];
}

extern "C" void kernel_launch(void* const* d_in, const int* in_sizes, int n_in,
                              void* d_out, int out_size, void* d_ws, size_t ws_size,
                              hipStream_t stream)
{
    const int*   ids    = (const int*)d_in[0];
    const int*   mask   = (const int*)d_in[1];
    const float* emb    = (const float*)d_in[2];
    const float* norm_w = (const float*)d_in[3];
    const float* Wi     = (const float*)d_in[4];
    const float* conv_w = (const float*)d_in[5];
    const float* conv_b = (const float*)d_in[6];
    const float* sB_w   = (const float*)d_in[7];
    const float* sC_w   = (const float*)d_in[8];
    const float* sD1_w  = (const float*)d_in[9];
    const float* sD2_w  = (const float*)d_in[10];
    const float* Amat   = (const float*)d_in[11];
    const float* Dp     = (const float*)d_in[12];
    const float* out_w  = (const float*)d_in[13];
    const float* cls_w  = (const float*)d_in[14];
    const float* cls_b  = (const float*)d_in[15];
    float* logits = (float*)d_out;

    // workspace layout (float units)
    float* ws = (float*)d_ws;
    size_t off = 0;
    float* x     = ws + off; off += (size_t)TT * DI;
    float* proj  = ws + off; off += (size_t)TT * 2 * DM;
    float* aconv = ws + off; off += (size_t)TT * DM;
    float* delta = ws + off; off += (size_t)TT * DM;      // h16 overlays (liveness disjoint)
    float* BCD   = ws + off; off += (size_t)TT * NW;
    float* Wcat  = ws + off; off += (size_t)NL * NW * DM;
    float2* PQ   = (float2*)(ws + off); off += (size_t)BB * NCH * DM * DS * 2;
    unsigned short* y16  = (unsigned short*)(ws + off); off += (size_t)TT * DM / 2;
    unsigned short* Wi16 = (unsigned short*)(ws + off); off += (size_t)2 * DM * DI / 2;
    unsigned short* Wo16 = (unsigned short*)(ws + off); off += (size_t)DI * DM / 2;
    unsigned short* dd16 = (unsigned short*)(ws + off); off += (size_t)TT * DD / 2;
    unsigned short* W216 = (unsigned short*)(ws + off); off += (size_t)DM * DD / 2;
    if (ws_size < off * sizeof(float)) return;  // fail loud

    unsigned short* h16 = (unsigned short*)delta;   // TT*DI bf16, dead before delta written

    embed_kernel<<<TT, DI / 4, 0, stream>>>(ids, mask, emb, x);
    concat_w_kernel<<<dim3(NW, NL), 256, 0, stream>>>(sB_w, sC_w, sD1_w, Wcat);

    for (int l = 0; l < NL; ++l) {
        const float* Wi_l  = Wi    + (size_t)l * 2 * DM * DI;
        const float* cw_l  = conv_w + (size_t)l * DM * KC;
        const float* cb_l  = conv_b + (size_t)l * DM;
        const float* W2_l  = sD2_w + (size_t)l * DM * DD;
        const float* A_l   = Amat  + (size_t)l * DM * DS;
        const float* Dp_l  = Dp    + (size_t)l * DM;
        const float* Wo_l  = out_w + (size_t)l * DI * DM;
        const float* nw_l  = norm_w + (size_t)l * DI;
        const float* Wcat_l = Wcat + (size_t)l * NW * DM;

        // weight conversions for this layer
        f32_to_bf16<<<(2 * DM * DI / 8 + 255) / 256, 256, 0, stream>>>(Wi_l, Wi16, 2 * DM * DI);
        f32_to_bf16<<<(DI * DM / 8 + 255) / 256, 256, 0, stream>>>(Wo_l, Wo16, DI * DM);
        f32_to_bf16<<<(DM * DD / 8 + 255) / 256, 256, 0, stream>>>(W2_l, W216, DM * DD);

        rmsnorm_kernel<<<TT, 256, 0, stream>>>(x, nw_l, h16);

        // proj = h @ Wi^T : M=TT, N=2*DM, K=DI  (bf16 MFMA)
        gemm_bf16<<<dim3(2 * DM / 128, TT / 128), 256, 0, stream>>>(
            h16, Wi16, nullptr, nullptr, proj, TT, 2 * DM, DI, DI, DI, 2 * DM, 0);

        conv_silu_kernel<<<dim3(TT, DM / 256), 256, 0, stream>>>(proj, cw_l, cb_l, aconv);

        // BCD = aconv @ Wcat^T (Bm | Cm | dd1) + dd1 bf16 sidecar
        gemm_skinny<<<TT / 32, 256, 0, stream>>>(aconv, Wcat_l, BCD, dd16);

        // delta = softplus(Dp + dd1 @ W2^T) : M=TT, N=DM, K=DD (bf16 MFMA)
        gemm_bf16<<<dim3(DM / 128, TT / 128), 256, 0, stream>>>(
            dd16, W216, nullptr, Dp_l, delta, TT, DM, DD, DD, DD, DM, 1);

        // chunk-parallel scan (R3 replay-proven kernels)
        scan_pass1<<<dim3(DM / 16, NCH, BB), 256, 0, stream>>>(
            delta, aconv, BCD, A_l, PQ);
        scan_carry<<<BB * DM * DS / 256, 256, 0, stream>>>(PQ);
        scan_pass2<<<dim3(DM / 16, NCH, BB), 256, 0, stream>>>(
            delta, aconv, BCD, proj, A_l, Dp_l, PQ, y16);

        // x = x + y @ Wo^T : M=TT, N=DI, K=DM  (bf16 MFMA)
        gemm_bf16<<<dim3(DI / 128, TT / 128), 256, 0, stream>>>(
            y16, Wo16, x, nullptr, x, TT, DI, DM, DM, DM, DI, 0);
    }

    cls_kernel<<<TT, 64, 0, stream>>>(x, cls_w, cls_b, logits);
}

// Round 7
// 891.224 us; speedup vs baseline: 5.4185x; 1.0973x over previous
//
#include <hip/hip_runtime.h>
#include <hip/hip_bf16.h>
#include <math.h>

// Problem constants
#define NLAB 9
#define NL   2
#define DI   768
#define DM   1536
#define DS   16
#define KC   4
#define DD   96
#define BB   2
#define SS   2048
#define TT   (BB*SS)
#define EPSF 1e-6f

// chunked scan config
#define NCH  32
#define CL   (SS/NCH)   // 64

// skinny fused projection width: 16 (B) + 16 (C) + 96 (dd1)
#define NW   128

typedef __attribute__((ext_vector_type(4))) float f32x4;
typedef __attribute__((ext_vector_type(8))) short bf16x8;
typedef __attribute__((ext_vector_type(4))) unsigned short us4;

__device__ __forceinline__ float siluf(float x) { return x / (1.f + __expf(-x)); }
__device__ __forceinline__ float softplusf(float x) { return x > 15.f ? x : log1pf(__expf(x)); }

// f32 -> bf16 (RNE, finite inputs)
__device__ __forceinline__ unsigned short f2bf(float f) {
    unsigned u = __float_as_uint(f);
    return (unsigned short)((u + 0x7fffu + ((u >> 16) & 1u)) >> 16);
}

__global__ void f32_to_bf16(const float* __restrict__ src,
                            unsigned short* __restrict__ dst, int n)
{
    int i = (blockIdx.x * 256 + threadIdx.x) * 8;
    if (i >= n) return;
    float4 a = *(const float4*)(src + i);
    float4 b = *(const float4*)(src + i + 4);
    union { unsigned short s[8]; uint4 v; } o;
    o.s[0] = f2bf(a.x); o.s[1] = f2bf(a.y); o.s[2] = f2bf(a.z); o.s[3] = f2bf(a.w);
    o.s[4] = f2bf(b.x); o.s[5] = f2bf(b.y); o.s[6] = f2bf(b.z); o.s[7] = f2bf(b.w);
    *(uint4*)(dst + i) = o.v;
}

// x[t,:] = emb[ids[t],:] * mask[t]
__global__ void embed_kernel(const int* __restrict__ ids, const int* __restrict__ mask,
                             const float* __restrict__ emb, float* __restrict__ x)
{
    int t = blockIdx.x;
    int i = threadIdx.x;
    float m = (float)mask[t];
    int id = ids[t];
    float4 v = ((const float4*)(emb + (size_t)id * DI))[i];
    v.x *= m; v.y *= m; v.z *= m; v.w *= m;
    ((float4*)(x + (size_t)t * DI))[i] = v;
}

// h16[t,:] = bf16( x[t,:] * rsqrt(mean(x^2)+eps) * w )
__global__ void rmsnorm_kernel(const float* __restrict__ x, const float* __restrict__ w,
                               unsigned short* __restrict__ h)
{
    __shared__ float red[4];
    int t = blockIdx.x;
    const float* xr = x + (size_t)t * DI;
    float ss = 0.f;
    for (int i = threadIdx.x; i < DI; i += 256) { float v = xr[i]; ss += v * v; }
    #pragma unroll
    for (int m = 1; m < 64; m <<= 1) ss += __shfl_xor(ss, m, 64);
    if ((threadIdx.x & 63) == 0) red[threadIdx.x >> 6] = ss;
    __syncthreads();
    float scale = rsqrtf((red[0] + red[1] + red[2] + red[3]) * (1.f / DI) + EPSF);
    for (int i = threadIdx.x; i < DI; i += 256)
        h[(size_t)t * DI + i] = f2bf(xr[i] * scale * w[i]);
}

// ---- bf16 MFMA GEMM (m97 structure; replay-proven) ----
__global__ __launch_bounds__(256) void gemm_bf16(
    const unsigned short* __restrict__ A, const unsigned short* __restrict__ B,
    const float* __restrict__ Rres, const float* __restrict__ bias,
    float* __restrict__ C, int M, int N, int K,
    int lda, int ldb, int ldc, int act)
{
    __shared__ unsigned short As[128 * 32];
    __shared__ unsigned short Bs[128 * 32];
    const int tid = threadIdx.x;
    const int wave = tid >> 6, lane = tid & 63;
    const int bm = blockIdx.y * 128, bn = blockIdx.x * 128;
    const int wm = (wave >> 1) * 64, wn = (wave & 1) * 64;
    const int lr = lane & 15, kh = lane >> 4;

    f32x4 acc[4][4] = {};

    const unsigned short* Arow = A + (size_t)bm * lda;
    const unsigned short* Brow = B + (size_t)bn * ldb;

    for (int kt = 0; kt < K; kt += 32) {
        #pragma unroll
        for (int it = 0; it < 2; ++it) {
            int rbase = it * 64 + wave * 16;
            int row = rbase + (lane >> 2);
            int c8 = (lane & 3) * 8;
            __builtin_amdgcn_global_load_lds(
                (const __attribute__((address_space(1))) unsigned int*)(Arow + (size_t)row * lda + kt + c8),
                (__attribute__((address_space(3))) unsigned int*)(As + rbase * 32),
                16, 0, 0);
            __builtin_amdgcn_global_load_lds(
                (const __attribute__((address_space(1))) unsigned int*)(Brow + (size_t)row * ldb + kt + c8),
                (__attribute__((address_space(3))) unsigned int*)(Bs + rbase * 32),
                16, 0, 0);
        }
        __syncthreads();

        bf16x8 af[4], bfr[4];
        #pragma unroll
        for (int i = 0; i < 4; ++i)
            af[i] = *(const bf16x8*)&As[(wm + i * 16 + lr) * 32 + kh * 8];
        #pragma unroll
        for (int j = 0; j < 4; ++j)
            bfr[j] = *(const bf16x8*)&Bs[(wn + j * 16 + lr) * 32 + kh * 8];
        #pragma unroll
        for (int i = 0; i < 4; ++i)
            #pragma unroll
            for (int j = 0; j < 4; ++j)
                acc[i][j] = __builtin_amdgcn_mfma_f32_16x16x32_bf16(af[i], bfr[j], acc[i][j], 0, 0, 0);
        __syncthreads();
    }

    #pragma unroll
    for (int i = 0; i < 4; ++i) {
        #pragma unroll
        for (int j = 0; j < 4; ++j) {
            #pragma unroll
            for (int r = 0; r < 4; ++r) {
                int row = bm + wm + i * 16 + kh * 4 + r;
                int col = bn + wn + j * 16 + lr;
                float v = acc[i][j][r];
                if (bias) v += bias[col];
                if (act == 1) v = softplusf(v);
                if (Rres) v += Rres[(size_t)row * ldc + col];
                C[(size_t)row * ldc + col] = v;
            }
        }
    }
}

// causal depthwise conv (K=4) + silu
__global__ void conv_silu_kernel(const float* __restrict__ proj, const float* __restrict__ cw,
                                 const float* __restrict__ cb, float* __restrict__ aconv)
{
    int t = blockIdx.x;
    int d = blockIdx.y * 256 + threadIdx.x;
    int p = t & (SS - 1);
    float acc = cb[d];
    #pragma unroll
    for (int j = 0; j < KC; ++j) {
        int pp = p - (KC - 1) + j;
        if (pp >= 0)
            acc += cw[d * KC + j] * proj[(size_t)(t - (KC - 1) + j) * (2 * DM) + d];
    }
    aconv[(size_t)t * DM + d] = siluf(acc);
}

// pack [WB;WC;W1] -> Wcat[l][128][DM]
__global__ void concat_w_kernel(const float* __restrict__ WB, const float* __restrict__ WC,
                                const float* __restrict__ W1, float* __restrict__ Wcat)
{
    int l = blockIdx.y;
    int row = blockIdx.x;
    const float* src;
    if (row < 16)      src = WB + (size_t)l * DS * DM + (size_t)row * DM;
    else if (row < 32) src = WC + (size_t)l * DS * DM + (size_t)(row - 16) * DM;
    else               src = W1 + (size_t)l * DD * DM + (size_t)(row - 32) * DM;
    float* dst = Wcat + ((size_t)l * NW + row) * DM;
    for (int i = threadIdx.x; i < DM / 4; i += 256)
        ((float4*)dst)[i] = ((const float4*)src)[i];
}

// BCD = aconv @ Wcat^T : M=TT, N=128, K=DM. Also emits dd1 (cols 32..127) as bf16.
__global__ __launch_bounds__(256) void gemm_skinny(
    const float* __restrict__ Amat, const float* __restrict__ Bmat,
    float* __restrict__ C, unsigned short* __restrict__ dd16)
{
    constexpr int BM = 32, BN = 128, BK = 32;
    __shared__ float As[BK][BM + 4];
    __shared__ float Bs[BK][BN + 4];
    const int tid = threadIdx.x;
    const int bm = blockIdx.x * BM;
    const int ty = tid >> 5, tx = tid & 31;
    float acc[4][4] = {};

    for (int kt = 0; kt < DM; kt += BK) {
        {
            int row = tid >> 3, kc = (tid & 7) << 2;
            float4 va = *(const float4*)(Amat + (size_t)(bm + row) * DM + kt + kc);
            As[kc + 0][row] = va.x; As[kc + 1][row] = va.y;
            As[kc + 2][row] = va.z; As[kc + 3][row] = va.w;
        }
        #pragma unroll
        for (int sidx = 0; sidx < 4; ++sidx) {
            int slot = tid + sidx * 256;
            int row = slot >> 3, kc = (slot & 7) << 2;
            float4 vb = *(const float4*)(Bmat + (size_t)row * DM + kt + kc);
            Bs[kc + 0][row] = vb.x; Bs[kc + 1][row] = vb.y;
            Bs[kc + 2][row] = vb.z; Bs[kc + 3][row] = vb.w;
        }
        __syncthreads();
        #pragma unroll
        for (int kk = 0; kk < BK; ++kk) {
            float4 a = *(const float4*)&As[kk][ty * 4];
            float4 b = *(const float4*)&Bs[kk][tx * 4];
            float av[4] = {a.x, a.y, a.z, a.w};
            float bv[4] = {b.x, b.y, b.z, b.w};
            #pragma unroll
            for (int i = 0; i < 4; ++i)
                #pragma unroll
                for (int j = 0; j < 4; ++j)
                    acc[i][j] += av[i] * bv[j];
        }
        __syncthreads();
    }
    #pragma unroll
    for (int i = 0; i < 4; ++i) {
        int row = bm + ty * 4 + i;
        float4 v = make_float4(acc[i][0], acc[i][1], acc[i][2], acc[i][3]);
        *(float4*)(C + (size_t)row * NW + tx * 4) = v;
        if (tx >= 8) {
            us4 u = { f2bf(v.x), f2bf(v.y), f2bf(v.z), f2bf(v.w) };
            *(us4*)(dd16 + (size_t)row * DD + tx * 4 - 32) = u;
        }
    }
}

// ---- chunk-parallel selective scan: thread-per-d, s-states in registers ----
// Boring rewrite: no global type-puns, no manual prefetch, native float2 PQ access,
// LDS tiles declared as float4 so vector reads need no casts.
// grid (DM/256, NCH, BB), block 256 (one thread per d).
__global__ __launch_bounds__(256) void scan_pass1(
    const float* __restrict__ delta, const float* __restrict__ aconv,
    const float* __restrict__ BCD, const float* __restrict__ Amat,
    float2* __restrict__ PQ)
{
    __shared__ float4 sB4[CL][DS / 4];
    int b = blockIdx.z, c = blockIdx.y;
    int d = blockIdx.x * 256 + threadIdx.x;
    size_t rowbase = (size_t)b * SS + (size_t)c * CL;

    for (int i = threadIdx.x; i < CL * DS; i += 256)
        ((float*)sB4)[i] = BCD[(rowbase + (i >> 4)) * NW + (i & 15)];
    __syncthreads();

    float negA[DS], hid[DS];
    #pragma unroll
    for (int s = 0; s < DS; ++s) {
        negA[s] = -Amat[(size_t)d * DS + s];
        hid[s] = 0.f;
    }
    float cum = 0.f;

    const float* dp = delta + rowbase * DM + d;
    const float* ap = aconv + rowbase * DM + d;
    for (int t = 0; t < CL; ++t) {
        float dt = dp[(size_t)t * DM];
        float av = ap[(size_t)t * DM];
        cum += dt;
        float xv = dt * av;
        #pragma unroll
        for (int j = 0; j < DS / 4; ++j) {
            float4 bv = sB4[t][j];
            hid[4*j+0] = __expf(dt * negA[4*j+0]) * hid[4*j+0] + xv * bv.x;
            hid[4*j+1] = __expf(dt * negA[4*j+1]) * hid[4*j+1] + xv * bv.y;
            hid[4*j+2] = __expf(dt * negA[4*j+2]) * hid[4*j+2] + xv * bv.z;
            hid[4*j+3] = __expf(dt * negA[4*j+3]) * hid[4*j+3] + xv * bv.w;
        }
    }
    float2* out = PQ + ((size_t)(b * NCH + c) * DM + d) * DS;
    #pragma unroll
    for (int s = 0; s < DS; ++s)
        out[s] = make_float2(__expf(cum * negA[s]), hid[s]);
}

// 49152 chains, NCH sequential chunk steps each; rewrites .x = carry-in
__global__ void scan_carry(float2* __restrict__ PQ)
{
    int idx = blockIdx.x * 256 + threadIdx.x;
    int b = idx / (DM * DS);
    int r = idx - b * (DM * DS);
    float carry = 0.f;
    for (int c = 0; c < NCH; ++c) {
        size_t o = (size_t)(b * NCH + c) * (DM * DS) + r;
        float2 pq = PQ[o];
        PQ[o].x = carry;
        carry = pq.x * carry + pq.y;
    }
}

// pass2: re-run seeded with carry; y16 = bf16((hid·Cm + Dp*av) * silu(gate))
__global__ __launch_bounds__(256) void scan_pass2(
    const float* __restrict__ delta, const float* __restrict__ aconv,
    const float* __restrict__ BCD,
    const float* __restrict__ proj, const float* __restrict__ Amat,
    const float* __restrict__ Dp, const float2* __restrict__ PQ,
    unsigned short* __restrict__ y)
{
    __shared__ float4 sB4[CL][DS / 4];
    __shared__ float4 sC4[CL][DS / 4];
    int b = blockIdx.z, c = blockIdx.y;
    int d = blockIdx.x * 256 + threadIdx.x;
    size_t rowbase = (size_t)b * SS + (size_t)c * CL;

    for (int i = threadIdx.x; i < CL * DS; i += 256) {
        size_t row = rowbase + (i >> 4);
        ((float*)sB4)[i] = BCD[row * NW + (i & 15)];
        ((float*)sC4)[i] = BCD[row * NW + 16 + (i & 15)];
    }
    __syncthreads();

    float negA[DS], hid[DS];
    const float2* pin = PQ + ((size_t)(b * NCH + c) * DM + d) * DS;
    #pragma unroll
    for (int s = 0; s < DS; ++s) {
        negA[s] = -Amat[(size_t)d * DS + s];
        hid[s] = pin[s].x;            // carry-in
    }
    float Dpd = Dp[d];

    const float* dp = delta + rowbase * DM + d;
    const float* ap = aconv + rowbase * DM + d;
    const float* gp = proj + rowbase * (2 * DM) + DM + d;
    unsigned short* yp = y + rowbase * DM + d;

    for (int t = 0; t < CL; ++t) {
        float dt = dp[(size_t)t * DM];
        float av = ap[(size_t)t * DM];
        float g  = gp[(size_t)t * (2 * DM)];
        float xv = dt * av;
        float acc0 = 0.f, acc1 = 0.f, acc2 = 0.f, acc3 = 0.f;
        #pragma unroll
        for (int j = 0; j < DS / 4; ++j) {
            float4 bv = sB4[t][j];
            float4 cv = sC4[t][j];
            hid[4*j+0] = __expf(dt * negA[4*j+0]) * hid[4*j+0] + xv * bv.x;
            hid[4*j+1] = __expf(dt * negA[4*j+1]) * hid[4*j+1] + xv * bv.y;
            hid[4*j+2] = __expf(dt * negA[4*j+2]) * hid[4*j+2] + xv * bv.z;
            hid[4*j+3] = __expf(dt * negA[4*j+3]) * hid[4*j+3] + xv * bv.w;
            acc0 += hid[4*j+0] * cv.x;
            acc1 += hid[4*j+1] * cv.y;
            acc2 += hid[4*j+2] * cv.z;
            acc3 += hid[4*j+3] * cv.w;
        }
        float contrib = (acc0 + acc1) + (acc2 + acc3);
        yp[(size_t)t * DM] = f2bf((contrib + Dpd * av) * siluf(g));
    }
}

// logits
__global__ void cls_kernel(const float* __restrict__ x, const float* __restrict__ W,
                           const float* __restrict__ bias, float* __restrict__ out)
{
    int t = blockIdx.x;
    int lane = threadIdx.x;
    const float* xr = x + (size_t)t * DI;
    float acc[NLAB];
    #pragma unroll
    for (int n = 0; n < NLAB; ++n) acc[n] = 0.f;
    for (int i = lane; i < DI; i += 64) {
        float xv = xr[i];
        #pragma unroll
        for (int n = 0; n < NLAB; ++n) acc[n] += xv * W[(size_t)n * DI + i];
    }
    #pragma unroll
    for (int n = 0; n < NLAB; ++n)
        #pragma unroll
        for (int m = 1; m < 64; m <<= 1) acc[n] += __shfl_xor(acc[n], m, 64);
    if (lane < NLAB) out[(size_t)t * NLAB + lane] = acc[lane] + bias[lane];
}

extern "C" void kernel_launch(void* const* d_in, const int* in_sizes, int n_in,
                              void* d_out, int out_size, void* d_ws, size_t ws_size,
                              hipStream_t stream)
{
    const int*   ids    = (const int*)d_in[0];
    const int*   mask   = (const int*)d_in[1];
    const float* emb    = (const float*)d_in[2];
    const float* norm_w = (const float*)d_in[3];
    const float* Wi     = (const float*)d_in[4];
    const float* conv_w = (const float*)d_in[5];
    const float* conv_b = (const float*)d_in[6];
    const float* sB_w   = (const float*)d_in[7];
    const float* sC_w   = (const float*)d_in[8];
    const float* sD1_w  = (const float*)d_in[9];
    const float* sD2_w  = (const float*)d_in[10];
    const float* Amat   = (const float*)d_in[11];
    const float* Dp     = (const float*)d_in[12];
    const float* out_w  = (const float*)d_in[13];
    const float* cls_w  = (const float*)d_in[14];
    const float* cls_b  = (const float*)d_in[15];
    float* logits = (float*)d_out;

    // workspace layout (float units)
    float* ws = (float*)d_ws;
    size_t off = 0;
    float* x     = ws + off; off += (size_t)TT * DI;
    float* proj  = ws + off; off += (size_t)TT * 2 * DM;
    float* aconv = ws + off; off += (size_t)TT * DM;
    float* delta = ws + off; off += (size_t)TT * DM;      // h16 overlays (liveness disjoint)
    float* BCD   = ws + off; off += (size_t)TT * NW;
    float* Wcat  = ws + off; off += (size_t)NL * NW * DM;
    float2* PQ   = (float2*)(ws + off); off += (size_t)BB * NCH * DM * DS * 2;
    unsigned short* y16  = (unsigned short*)(ws + off); off += (size_t)TT * DM / 2;
    unsigned short* Wi16 = (unsigned short*)(ws + off); off += (size_t)2 * DM * DI / 2;
    unsigned short* Wo16 = (unsigned short*)(ws + off); off += (size_t)DI * DM / 2;
    unsigned short* dd16 = (unsigned short*)(ws + off); off += (size_t)TT * DD / 2;
    unsigned short* W216 = (unsigned short*)(ws + off); off += (size_t)DM * DD / 2;
    if (ws_size < off * sizeof(float)) return;  // fail loud

    unsigned short* h16 = (unsigned short*)delta;   // TT*DI bf16, dead before delta written

    embed_kernel<<<TT, DI / 4, 0, stream>>>(ids, mask, emb, x);
    concat_w_kernel<<<dim3(NW, NL), 256, 0, stream>>>(sB_w, sC_w, sD1_w, Wcat);

    for (int l = 0; l < NL; ++l) {
        const float* Wi_l  = Wi    + (size_t)l * 2 * DM * DI;
        const float* cw_l  = conv_w + (size_t)l * DM * KC;
        const float* cb_l  = conv_b + (size_t)l * DM;
        const float* W2_l  = sD2_w + (size_t)l * DM * DD;
        const float* A_l   = Amat  + (size_t)l * DM * DS;
        const float* Dp_l  = Dp    + (size_t)l * DM;
        const float* Wo_l  = out_w + (size_t)l * DI * DM;
        const float* nw_l  = norm_w + (size_t)l * DI;
        const float* Wcat_l = Wcat + (size_t)l * NW * DM;

        // weight conversions for this layer
        f32_to_bf16<<<(2 * DM * DI / 8 + 255) / 256, 256, 0, stream>>>(Wi_l, Wi16, 2 * DM * DI);
        f32_to_bf16<<<(DI * DM / 8 + 255) / 256, 256, 0, stream>>>(Wo_l, Wo16, DI * DM);
        f32_to_bf16<<<(DM * DD / 8 + 255) / 256, 256, 0, stream>>>(W2_l, W216, DM * DD);

        rmsnorm_kernel<<<TT, 256, 0, stream>>>(x, nw_l, h16);

        // proj = h @ Wi^T : M=TT, N=2*DM, K=DI  (bf16 MFMA)
        gemm_bf16<<<dim3(2 * DM / 128, TT / 128), 256, 0, stream>>>(
            h16, Wi16, nullptr, nullptr, proj, TT, 2 * DM, DI, DI, DI, 2 * DM, 0);

        conv_silu_kernel<<<dim3(TT, DM / 256), 256, 0, stream>>>(proj, cw_l, cb_l, aconv);

        // BCD = aconv @ Wcat^T (Bm | Cm | dd1) + dd1 bf16 sidecar
        gemm_skinny<<<TT / 32, 256, 0, stream>>>(aconv, Wcat_l, BCD, dd16);

        // delta = softplus(Dp + dd1 @ W2^T) : M=TT, N=DM, K=DD (bf16 MFMA)
        gemm_bf16<<<dim3(DM / 128, TT / 128), 256, 0, stream>>>(
            dd16, W216, nullptr, Dp_l, delta, TT, DM, DD, DD, DD, DM, 1);

        // chunk-parallel scan (thread-per-d, boring rewrite)
        scan_pass1<<<dim3(DM / 256, NCH, BB), 256, 0, stream>>>(
            delta, aconv, BCD, A_l, PQ);
        scan_carry<<<BB * DM * DS / 256, 256, 0, stream>>>(PQ);
        scan_pass2<<<dim3(DM / 256, NCH, BB), 256, 0, stream>>>(
            delta, aconv, BCD, proj, A_l, Dp_l, PQ, y16);

        // x = x + y @ Wo^T : M=TT, N=DI, K=DM  (bf16 MFMA)
        gemm_bf16<<<dim3(DI / 128, TT / 128), 256, 0, stream>>>(
            y16, Wo16, x, nullptr, x, TT, DI, DM, DM, DM, DI, 0);
    }

    cls_kernel<<<TT, 64, 0, stream>>>(x, cls_w, cls_b, logits);
}

// Round 8
// 771.059 us; speedup vs baseline: 6.2630x; 1.1558x over previous
//
#include <hip/hip_runtime.h>
#include <hip/hip_bf16.h>
#include <math.h>

// Problem constants
#define NLAB 9
#define NL   2
#define DI   768
#define DM   1536
#define DS   16
#define KC   4
#define DD   96
#define BB   2
#define SS   2048
#define TT   (BB*SS)
#define EPSF 1e-6f

// chunked scan config
#define NCH  32
#define CL   (SS/NCH)   // 64

// skinny fused projection width: 16 (B) + 16 (C) + 96 (dd1)
#define NW   128
// split-K factor for the skinny GEMM (K=DM=1536 -> 8 x 192)
#define KS   8
#define KSL  (DM/KS)    // 192

typedef __attribute__((ext_vector_type(4))) float f32x4;
typedef __attribute__((ext_vector_type(8))) short bf16x8;
typedef __attribute__((ext_vector_type(4))) unsigned short us4;

__device__ __forceinline__ float siluf(float x) { return x / (1.f + __expf(-x)); }
__device__ __forceinline__ float softplusf(float x) { return x > 15.f ? x : log1pf(__expf(x)); }

// f32 -> bf16 (RNE, finite inputs)
__device__ __forceinline__ unsigned short f2bf(float f) {
    unsigned u = __float_as_uint(f);
    return (unsigned short)((u + 0x7fffu + ((u >> 16) & 1u)) >> 16);
}

__global__ void f32_to_bf16(const float* __restrict__ src,
                            unsigned short* __restrict__ dst, int n)
{
    int i = (blockIdx.x * 256 + threadIdx.x) * 8;
    if (i >= n) return;
    float4 a = *(const float4*)(src + i);
    float4 b = *(const float4*)(src + i + 4);
    union { unsigned short s[8]; uint4 v; } o;
    o.s[0] = f2bf(a.x); o.s[1] = f2bf(a.y); o.s[2] = f2bf(a.z); o.s[3] = f2bf(a.w);
    o.s[4] = f2bf(b.x); o.s[5] = f2bf(b.y); o.s[6] = f2bf(b.z); o.s[7] = f2bf(b.w);
    *(uint4*)(dst + i) = o.v;
}

// x[t,:] = emb[ids[t],:] * mask[t]
__global__ void embed_kernel(const int* __restrict__ ids, const int* __restrict__ mask,
                             const float* __restrict__ emb, float* __restrict__ x)
{
    int t = blockIdx.x;
    int i = threadIdx.x;
    float m = (float)mask[t];
    int id = ids[t];
    float4 v = ((const float4*)(emb + (size_t)id * DI))[i];
    v.x *= m; v.y *= m; v.z *= m; v.w *= m;
    ((float4*)(x + (size_t)t * DI))[i] = v;
}

// h16[t,:] = bf16( x[t,:] * rsqrt(mean(x^2)+eps) * w )
__global__ void rmsnorm_kernel(const float* __restrict__ x, const float* __restrict__ w,
                               unsigned short* __restrict__ h)
{
    __shared__ float red[4];
    int t = blockIdx.x;
    const float* xr = x + (size_t)t * DI;
    float ss = 0.f;
    for (int i = threadIdx.x; i < DI; i += 256) { float v = xr[i]; ss += v * v; }
    #pragma unroll
    for (int m = 1; m < 64; m <<= 1) ss += __shfl_xor(ss, m, 64);
    if ((threadIdx.x & 63) == 0) red[threadIdx.x >> 6] = ss;
    __syncthreads();
    float scale = rsqrtf((red[0] + red[1] + red[2] + red[3]) * (1.f / DI) + EPSF);
    for (int i = threadIdx.x; i < DI; i += 256)
        h[(size_t)t * DI + i] = f2bf(xr[i] * scale * w[i]);
}

// ---- bf16 MFMA GEMM (m97 structure; replay-proven) ----
__global__ __launch_bounds__(256) void gemm_bf16(
    const unsigned short* __restrict__ A, const unsigned short* __restrict__ B,
    const float* __restrict__ Rres, const float* __restrict__ bias,
    float* __restrict__ C, int M, int N, int K,
    int lda, int ldb, int ldc, int act)
{
    __shared__ unsigned short As[128 * 32];
    __shared__ unsigned short Bs[128 * 32];
    const int tid = threadIdx.x;
    const int wave = tid >> 6, lane = tid & 63;
    const int bm = blockIdx.y * 128, bn = blockIdx.x * 128;
    const int wm = (wave >> 1) * 64, wn = (wave & 1) * 64;
    const int lr = lane & 15, kh = lane >> 4;

    f32x4 acc[4][4] = {};

    const unsigned short* Arow = A + (size_t)bm * lda;
    const unsigned short* Brow = B + (size_t)bn * ldb;

    for (int kt = 0; kt < K; kt += 32) {
        #pragma unroll
        for (int it = 0; it < 2; ++it) {
            int rbase = it * 64 + wave * 16;
            int row = rbase + (lane >> 2);
            int c8 = (lane & 3) * 8;
            __builtin_amdgcn_global_load_lds(
                (const __attribute__((address_space(1))) unsigned int*)(Arow + (size_t)row * lda + kt + c8),
                (__attribute__((address_space(3))) unsigned int*)(As + rbase * 32),
                16, 0, 0);
            __builtin_amdgcn_global_load_lds(
                (const __attribute__((address_space(1))) unsigned int*)(Brow + (size_t)row * ldb + kt + c8),
                (__attribute__((address_space(3))) unsigned int*)(Bs + rbase * 32),
                16, 0, 0);
        }
        __syncthreads();

        bf16x8 af[4], bfr[4];
        #pragma unroll
        for (int i = 0; i < 4; ++i)
            af[i] = *(const bf16x8*)&As[(wm + i * 16 + lr) * 32 + kh * 8];
        #pragma unroll
        for (int j = 0; j < 4; ++j)
            bfr[j] = *(const bf16x8*)&Bs[(wn + j * 16 + lr) * 32 + kh * 8];
        #pragma unroll
        for (int i = 0; i < 4; ++i)
            #pragma unroll
            for (int j = 0; j < 4; ++j)
                acc[i][j] = __builtin_amdgcn_mfma_f32_16x16x32_bf16(af[i], bfr[j], acc[i][j], 0, 0, 0);
        __syncthreads();
    }

    #pragma unroll
    for (int i = 0; i < 4; ++i) {
        #pragma unroll
        for (int j = 0; j < 4; ++j) {
            #pragma unroll
            for (int r = 0; r < 4; ++r) {
                int row = bm + wm + i * 16 + kh * 4 + r;
                int col = bn + wn + j * 16 + lr;
                float v = acc[i][j][r];
                if (bias) v += bias[col];
                if (act == 1) v = softplusf(v);
                if (Rres) v += Rres[(size_t)row * ldc + col];
                C[(size_t)row * ldc + col] = v;
            }
        }
    }
}

// split-K skinny GEMM: Part[ks] = aconv16[bm:bm+128, ks*192:(ks+1)*192] @ Wcat16^T
// grid (TT/128, KS), 256 threads; same staging/MFMA pattern as gemm_bf16.
__global__ __launch_bounds__(256) void gemm_skinny_bf16(
    const unsigned short* __restrict__ A, const unsigned short* __restrict__ B,
    float* __restrict__ Part)
{
    __shared__ unsigned short As[128 * 32];
    __shared__ unsigned short Bs[128 * 32];
    const int tid = threadIdx.x;
    const int wave = tid >> 6, lane = tid & 63;
    const int bm = blockIdx.x * 128;
    const int ks = blockIdx.y;
    const int k0 = ks * KSL;
    const int wm = (wave >> 1) * 64, wn = (wave & 1) * 64;
    const int lr = lane & 15, kh = lane >> 4;

    f32x4 acc[4][4] = {};

    const unsigned short* Arow = A + (size_t)bm * DM;
    const unsigned short* Brow = B;   // 128 x DM

    for (int kt = 0; kt < KSL; kt += 32) {
        #pragma unroll
        for (int it = 0; it < 2; ++it) {
            int rbase = it * 64 + wave * 16;
            int row = rbase + (lane >> 2);
            int c8 = (lane & 3) * 8;
            __builtin_amdgcn_global_load_lds(
                (const __attribute__((address_space(1))) unsigned int*)(Arow + (size_t)row * DM + k0 + kt + c8),
                (__attribute__((address_space(3))) unsigned int*)(As + rbase * 32),
                16, 0, 0);
            __builtin_amdgcn_global_load_lds(
                (const __attribute__((address_space(1))) unsigned int*)(Brow + (size_t)row * DM + k0 + kt + c8),
                (__attribute__((address_space(3))) unsigned int*)(Bs + rbase * 32),
                16, 0, 0);
        }
        __syncthreads();

        bf16x8 af[4], bfr[4];
        #pragma unroll
        for (int i = 0; i < 4; ++i)
            af[i] = *(const bf16x8*)&As[(wm + i * 16 + lr) * 32 + kh * 8];
        #pragma unroll
        for (int j = 0; j < 4; ++j)
            bfr[j] = *(const bf16x8*)&Bs[(wn + j * 16 + lr) * 32 + kh * 8];
        #pragma unroll
        for (int i = 0; i < 4; ++i)
            #pragma unroll
            for (int j = 0; j < 4; ++j)
                acc[i][j] = __builtin_amdgcn_mfma_f32_16x16x32_bf16(af[i], bfr[j], acc[i][j], 0, 0, 0);
        __syncthreads();
    }

    float* out = Part + (size_t)ks * TT * NW;
    #pragma unroll
    for (int i = 0; i < 4; ++i) {
        #pragma unroll
        for (int j = 0; j < 4; ++j) {
            #pragma unroll
            for (int r = 0; r < 4; ++r) {
                int row = bm + wm + i * 16 + kh * 4 + r;
                int col = wn + j * 16 + lr;
                out[(size_t)row * NW + col] = acc[i][j][r];
            }
        }
    }
}

// sum KS partials -> BCD f32; cols 32..127 also -> dd16 bf16
__global__ void skinny_reduce(const float* __restrict__ Part,
                              float* __restrict__ BCD, unsigned short* __restrict__ dd16)
{
    int idx = blockIdx.x * 256 + threadIdx.x;     // over TT*NW
    float s = 0.f;
    #pragma unroll
    for (int ks = 0; ks < KS; ++ks)
        s += Part[(size_t)ks * TT * NW + idx];
    BCD[idx] = s;
    int col = idx & (NW - 1);
    if (col >= 32)
        dd16[(size_t)(idx >> 7) * DD + (col - 32)] = f2bf(s);
}

// causal depthwise conv (K=4) + silu; emits f32 (scan) and bf16 (skinny GEMM)
__global__ void conv_silu_kernel(const float* __restrict__ proj, const float* __restrict__ cw,
                                 const float* __restrict__ cb, float* __restrict__ aconv,
                                 unsigned short* __restrict__ aconv16)
{
    int t = blockIdx.x;
    int d = blockIdx.y * 256 + threadIdx.x;
    int p = t & (SS - 1);
    float acc = cb[d];
    #pragma unroll
    for (int j = 0; j < KC; ++j) {
        int pp = p - (KC - 1) + j;
        if (pp >= 0)
            acc += cw[d * KC + j] * proj[(size_t)(t - (KC - 1) + j) * (2 * DM) + d];
    }
    float v = siluf(acc);
    aconv[(size_t)t * DM + d] = v;
    aconv16[(size_t)t * DM + d] = f2bf(v);
}

// pack [WB;WC;W1] -> Wcat16[l][128][DM] (bf16)
__global__ void concat_w_kernel(const float* __restrict__ WB, const float* __restrict__ WC,
                                const float* __restrict__ W1, unsigned short* __restrict__ Wcat16)
{
    int l = blockIdx.y;
    int row = blockIdx.x;
    const float* src;
    if (row < 16)      src = WB + (size_t)l * DS * DM + (size_t)row * DM;
    else if (row < 32) src = WC + (size_t)l * DS * DM + (size_t)(row - 16) * DM;
    else               src = W1 + (size_t)l * DD * DM + (size_t)(row - 32) * DM;
    unsigned short* dst = Wcat16 + ((size_t)l * NW + row) * DM;
    for (int i = threadIdx.x; i < DM / 4; i += 256) {
        float4 v = ((const float4*)src)[i];
        us4 u = { f2bf(v.x), f2bf(v.y), f2bf(v.z), f2bf(v.w) };
        *(us4*)(dst + i * 4) = u;
    }
}

// ---- chunk-parallel selective scan: thread-per-d, s-states in registers ----
__global__ __launch_bounds__(256) void scan_pass1(
    const float* __restrict__ delta, const float* __restrict__ aconv,
    const float* __restrict__ BCD, const float* __restrict__ Amat,
    float2* __restrict__ PQ)
{
    __shared__ float4 sB4[CL][DS / 4];
    int b = blockIdx.z, c = blockIdx.y;
    int d = blockIdx.x * 256 + threadIdx.x;
    size_t rowbase = (size_t)b * SS + (size_t)c * CL;

    for (int i = threadIdx.x; i < CL * DS; i += 256)
        ((float*)sB4)[i] = BCD[(rowbase + (i >> 4)) * NW + (i & 15)];
    __syncthreads();

    float negA[DS], hid[DS];
    #pragma unroll
    for (int s = 0; s < DS; ++s) {
        negA[s] = -Amat[(size_t)d * DS + s];
        hid[s] = 0.f;
    }
    float cum = 0.f;

    const float* dp = delta + rowbase * DM + d;
    const float* ap = aconv + rowbase * DM + d;
    for (int t = 0; t < CL; ++t) {
        float dt = dp[(size_t)t * DM];
        float av = ap[(size_t)t * DM];
        cum += dt;
        float xv = dt * av;
        #pragma unroll
        for (int j = 0; j < DS / 4; ++j) {
            float4 bv = sB4[t][j];
            hid[4*j+0] = __expf(dt * negA[4*j+0]) * hid[4*j+0] + xv * bv.x;
            hid[4*j+1] = __expf(dt * negA[4*j+1]) * hid[4*j+1] + xv * bv.y;
            hid[4*j+2] = __expf(dt * negA[4*j+2]) * hid[4*j+2] + xv * bv.z;
            hid[4*j+3] = __expf(dt * negA[4*j+3]) * hid[4*j+3] + xv * bv.w;
        }
    }
    float2* out = PQ + ((size_t)(b * NCH + c) * DM + d) * DS;
    #pragma unroll
    for (int s = 0; s < DS; ++s)
        out[s] = make_float2(__expf(cum * negA[s]), hid[s]);
}

// 49152 chains, NCH sequential chunk steps each; rewrites .x = carry-in
__global__ void scan_carry(float2* __restrict__ PQ)
{
    int idx = blockIdx.x * 256 + threadIdx.x;
    int b = idx / (DM * DS);
    int r = idx - b * (DM * DS);
    float carry = 0.f;
    for (int c = 0; c < NCH; ++c) {
        size_t o = (size_t)(b * NCH + c) * (DM * DS) + r;
        float2 pq = PQ[o];
        PQ[o].x = carry;
        carry = pq.x * carry + pq.y;
    }
}

// pass2: re-run seeded with carry; y16 = bf16((hid·Cm + Dp*av) * silu(gate))
__global__ __launch_bounds__(256) void scan_pass2(
    const float* __restrict__ delta, const float* __restrict__ aconv,
    const float* __restrict__ BCD,
    const float* __restrict__ proj, const float* __restrict__ Amat,
    const float* __restrict__ Dp, const float2* __restrict__ PQ,
    unsigned short* __restrict__ y)
{
    __shared__ float4 sB4[CL][DS / 4];
    __shared__ float4 sC4[CL][DS / 4];
    int b = blockIdx.z, c = blockIdx.y;
    int d = blockIdx.x * 256 + threadIdx.x;
    size_t rowbase = (size_t)b * SS + (size_t)c * CL;

    for (int i = threadIdx.x; i < CL * DS; i += 256) {
        size_t row = rowbase + (i >> 4);
        ((float*)sB4)[i] = BCD[row * NW + (i & 15)];
        ((float*)sC4)[i] = BCD[row * NW + 16 + (i & 15)];
    }
    __syncthreads();

    float negA[DS], hid[DS];
    const float2* pin = PQ + ((size_t)(b * NCH + c) * DM + d) * DS;
    #pragma unroll
    for (int s = 0; s < DS; ++s) {
        negA[s] = -Amat[(size_t)d * DS + s];
        hid[s] = pin[s].x;            // carry-in
    }
    float Dpd = Dp[d];

    const float* dp = delta + rowbase * DM + d;
    const float* ap = aconv + rowbase * DM + d;
    const float* gp = proj + rowbase * (2 * DM) + DM + d;
    unsigned short* yp = y + rowbase * DM + d;

    for (int t = 0; t < CL; ++t) {
        float dt = dp[(size_t)t * DM];
        float av = ap[(size_t)t * DM];
        float g  = gp[(size_t)t * (2 * DM)];
        float xv = dt * av;
        float acc0 = 0.f, acc1 = 0.f, acc2 = 0.f, acc3 = 0.f;
        #pragma unroll
        for (int j = 0; j < DS / 4; ++j) {
            float4 bv = sB4[t][j];
            float4 cv = sC4[t][j];
            hid[4*j+0] = __expf(dt * negA[4*j+0]) * hid[4*j+0] + xv * bv.x;
            hid[4*j+1] = __expf(dt * negA[4*j+1]) * hid[4*j+1] + xv * bv.y;
            hid[4*j+2] = __expf(dt * negA[4*j+2]) * hid[4*j+2] + xv * bv.z;
            hid[4*j+3] = __expf(dt * negA[4*j+3]) * hid[4*j+3] + xv * bv.w;
            acc0 += hid[4*j+0] * cv.x;
            acc1 += hid[4*j+1] * cv.y;
            acc2 += hid[4*j+2] * cv.z;
            acc3 += hid[4*j+3] * cv.w;
        }
        float contrib = (acc0 + acc1) + (acc2 + acc3);
        yp[(size_t)t * DM] = f2bf((contrib + Dpd * av) * siluf(g));
    }
}

// logits
__global__ void cls_kernel(const float* __restrict__ x, const float* __restrict__ W,
                           const float* __restrict__ bias, float* __restrict__ out)
{
    int t = blockIdx.x;
    int lane = threadIdx.x;
    const float* xr = x + (size_t)t * DI;
    float acc[NLAB];
    #pragma unroll
    for (int n = 0; n < NLAB; ++n) acc[n] = 0.f;
    for (int i = lane; i < DI; i += 64) {
        float xv = xr[i];
        #pragma unroll
        for (int n = 0; n < NLAB; ++n) acc[n] += xv * W[(size_t)n * DI + i];
    }
    #pragma unroll
    for (int n = 0; n < NLAB; ++n)
        #pragma unroll
        for (int m = 1; m < 64; m <<= 1) acc[n] += __shfl_xor(acc[n], m, 64);
    if (lane < NLAB) out[(size_t)t * NLAB + lane] = acc[lane] + bias[lane];
}

extern "C" void kernel_launch(void* const* d_in, const int* in_sizes, int n_in,
                              void* d_out, int out_size, void* d_ws, size_t ws_size,
                              hipStream_t stream)
{
    const int*   ids    = (const int*)d_in[0];
    const int*   mask   = (const int*)d_in[1];
    const float* emb    = (const float*)d_in[2];
    const float* norm_w = (const float*)d_in[3];
    const float* Wi     = (const float*)d_in[4];
    const float* conv_w = (const float*)d_in[5];
    const float* conv_b = (const float*)d_in[6];
    const float* sB_w   = (const float*)d_in[7];
    const float* sC_w   = (const float*)d_in[8];
    const float* sD1_w  = (const float*)d_in[9];
    const float* sD2_w  = (const float*)d_in[10];
    const float* Amat   = (const float*)d_in[11];
    const float* Dp     = (const float*)d_in[12];
    const float* out_w  = (const float*)d_in[13];
    const float* cls_w  = (const float*)d_in[14];
    const float* cls_b  = (const float*)d_in[15];
    float* logits = (float*)d_out;

    // workspace layout (float units)
    float* ws = (float*)d_ws;
    size_t off = 0;
    float* x     = ws + off; off += (size_t)TT * DI;
    float* proj  = ws + off; off += (size_t)TT * 2 * DM;
    float* aconv = ws + off; off += (size_t)TT * DM;
    float* delta = ws + off; off += (size_t)TT * DM;      // h16 overlays (liveness disjoint)
    float* BCD   = ws + off; off += (size_t)TT * NW;
    float* Part  = ws + off; off += (size_t)KS * TT * NW; // split-K partials
    float2* PQ   = (float2*)(ws + off); off += (size_t)BB * NCH * DM * DS * 2;
    unsigned short* y16   = (unsigned short*)(ws + off); off += (size_t)TT * DM / 2;
    unsigned short* aconv16 = (unsigned short*)(ws + off); off += (size_t)TT * DM / 2;
    unsigned short* Wi16  = (unsigned short*)(ws + off); off += (size_t)NL * 2 * DM * DI / 2;
    unsigned short* Wo16  = (unsigned short*)(ws + off); off += (size_t)NL * DI * DM / 2;
    unsigned short* W216  = (unsigned short*)(ws + off); off += (size_t)NL * DM * DD / 2;
    unsigned short* dd16  = (unsigned short*)(ws + off); off += (size_t)TT * DD / 2;
    unsigned short* Wcat16 = (unsigned short*)(ws + off); off += (size_t)NL * NW * DM / 2;
    if (ws_size < off * sizeof(float)) return;  // fail loud

    unsigned short* h16 = (unsigned short*)delta;   // TT*DI bf16, dead before delta written

    embed_kernel<<<TT, DI / 4, 0, stream>>>(ids, mask, emb, x);
    concat_w_kernel<<<dim3(NW, NL), 256, 0, stream>>>(sB_w, sC_w, sD1_w, Wcat16);

    // whole-tensor weight conversions (all layers at once)
    f32_to_bf16<<<(NL * 2 * DM * DI / 8 + 255) / 256, 256, 0, stream>>>(Wi, Wi16, NL * 2 * DM * DI);
    f32_to_bf16<<<(NL * DI * DM / 8 + 255) / 256, 256, 0, stream>>>(out_w, Wo16, NL * DI * DM);
    f32_to_bf16<<<(NL * DM * DD / 8 + 255) / 256, 256, 0, stream>>>(sD2_w, W216, NL * DM * DD);

    for (int l = 0; l < NL; ++l) {
        const float* cw_l  = conv_w + (size_t)l * DM * KC;
        const float* cb_l  = conv_b + (size_t)l * DM;
        const float* A_l   = Amat  + (size_t)l * DM * DS;
        const float* Dp_l  = Dp    + (size_t)l * DM;
        const float* nw_l  = norm_w + (size_t)l * DI;
        const unsigned short* Wi16_l  = Wi16  + (size_t)l * 2 * DM * DI;
        const unsigned short* Wo16_l  = Wo16  + (size_t)l * DI * DM;
        const unsigned short* W216_l  = W216  + (size_t)l * DM * DD;
        const unsigned short* Wcat16_l = Wcat16 + (size_t)l * NW * DM;

        rmsnorm_kernel<<<TT, 256, 0, stream>>>(x, nw_l, h16);

        // proj = h @ Wi^T : M=TT, N=2*DM, K=DI  (bf16 MFMA)
        gemm_bf16<<<dim3(2 * DM / 128, TT / 128), 256, 0, stream>>>(
            h16, Wi16_l, nullptr, nullptr, proj, TT, 2 * DM, DI, DI, DI, 2 * DM, 0);

        conv_silu_kernel<<<dim3(TT, DM / 256), 256, 0, stream>>>(proj, cw_l, cb_l, aconv, aconv16);

        // BCD = aconv @ Wcat^T (Bm | Cm | dd1), split-K MFMA + reduce
        gemm_skinny_bf16<<<dim3(TT / 128, KS), 256, 0, stream>>>(aconv16, Wcat16_l, Part);
        skinny_reduce<<<TT * NW / 256, 256, 0, stream>>>(Part, BCD, dd16);

        // delta = softplus(Dp + dd1 @ W2^T) : M=TT, N=DM, K=DD (bf16 MFMA)
        gemm_bf16<<<dim3(DM / 128, TT / 128), 256, 0, stream>>>(
            dd16, W216_l, nullptr, Dp_l, delta, TT, DM, DD, DD, DD, DM, 1);

        // chunk-parallel scan (thread-per-d)
        scan_pass1<<<dim3(DM / 256, NCH, BB), 256, 0, stream>>>(
            delta, aconv, BCD, A_l, PQ);
        scan_carry<<<BB * DM * DS / 256, 256, 0, stream>>>(PQ);
        scan_pass2<<<dim3(DM / 256, NCH, BB), 256, 0, stream>>>(
            delta, aconv, BCD, proj, A_l, Dp_l, PQ, y16);

        // x = x + y @ Wo^T : M=TT, N=DI, K=DM  (bf16 MFMA)
        gemm_bf16<<<dim3(DI / 128, TT / 128), 256, 0, stream>>>(
            y16, Wo16_l, x, nullptr, x, TT, DI, DM, DM, DM, DI, 0);
    }

    cls_kernel<<<TT, 64, 0, stream>>>(x, cls_w, cls_b, logits);
}

// Round 9
// 742.113 us; speedup vs baseline: 6.5073x; 1.0390x over previous
//
#include <hip/hip_runtime.h>
#include <hip/hip_bf16.h>
#include <math.h>

// Problem constants
#define NLAB 9
#define NL   2
#define DI   768
#define DM   1536
#define DS   16
#define KC   4
#define DD   96
#define BB   2
#define SS   2048
#define TT   (BB*SS)
#define EPSF 1e-6f

// chunked scan config
#define NCH  64
#define CL   (SS/NCH)   // 32

// skinny fused projection width: 16 (B) + 16 (C) + 96 (dd1)
#define NW   128
// split-K factor for the skinny GEMM (K=DM=1536 -> 8 x 192)
#define KS   8
#define KSL  (DM/KS)    // 192

typedef __attribute__((ext_vector_type(4))) float f32x4;
typedef __attribute__((ext_vector_type(8))) short bf16x8;
typedef __attribute__((ext_vector_type(4))) unsigned short us4;

__device__ __forceinline__ float siluf(float x) { return x / (1.f + __expf(-x)); }
__device__ __forceinline__ float softplusf(float x) { return x > 15.f ? x : log1pf(__expf(x)); }

// f32 -> bf16 (RNE, finite inputs)
__device__ __forceinline__ unsigned short f2bf(float f) {
    unsigned u = __float_as_uint(f);
    return (unsigned short)((u + 0x7fffu + ((u >> 16) & 1u)) >> 16);
}

__global__ void f32_to_bf16(const float* __restrict__ src,
                            unsigned short* __restrict__ dst, int n)
{
    int i = (blockIdx.x * 256 + threadIdx.x) * 8;
    if (i >= n) return;
    float4 a = *(const float4*)(src + i);
    float4 b = *(const float4*)(src + i + 4);
    union { unsigned short s[8]; uint4 v; } o;
    o.s[0] = f2bf(a.x); o.s[1] = f2bf(a.y); o.s[2] = f2bf(a.z); o.s[3] = f2bf(a.w);
    o.s[4] = f2bf(b.x); o.s[5] = f2bf(b.y); o.s[6] = f2bf(b.z); o.s[7] = f2bf(b.w);
    *(uint4*)(dst + i) = o.v;
}

// x[t,:] = emb[ids[t],:] * mask[t]
__global__ void embed_kernel(const int* __restrict__ ids, const int* __restrict__ mask,
                             const float* __restrict__ emb, float* __restrict__ x)
{
    int t = blockIdx.x;
    int i = threadIdx.x;
    float m = (float)mask[t];
    int id = ids[t];
    float4 v = ((const float4*)(emb + (size_t)id * DI))[i];
    v.x *= m; v.y *= m; v.z *= m; v.w *= m;
    ((float4*)(x + (size_t)t * DI))[i] = v;
}

// h16[t,:] = bf16( x[t,:] * rsqrt(mean(x^2)+eps) * w )
__global__ void rmsnorm_kernel(const float* __restrict__ x, const float* __restrict__ w,
                               unsigned short* __restrict__ h)
{
    __shared__ float red[4];
    int t = blockIdx.x;
    const float* xr = x + (size_t)t * DI;
    float ss = 0.f;
    for (int i = threadIdx.x; i < DI; i += 256) { float v = xr[i]; ss += v * v; }
    #pragma unroll
    for (int m = 1; m < 64; m <<= 1) ss += __shfl_xor(ss, m, 64);
    if ((threadIdx.x & 63) == 0) red[threadIdx.x >> 6] = ss;
    __syncthreads();
    float scale = rsqrtf((red[0] + red[1] + red[2] + red[3]) * (1.f / DI) + EPSF);
    for (int i = threadIdx.x; i < DI; i += 256)
        h[(size_t)t * DI + i] = f2bf(xr[i] * scale * w[i]);
}

// ---- bf16 MFMA GEMM (m97 structure; replay-proven) ----
// cstride: element stride of C (2 = write .x of a float2 array)
__global__ __launch_bounds__(256) void gemm_bf16(
    const unsigned short* __restrict__ A, const unsigned short* __restrict__ B,
    const float* __restrict__ Rres, const float* __restrict__ bias,
    float* __restrict__ C, int M, int N, int K,
    int lda, int ldb, int ldc, int act, int cstride)
{
    __shared__ unsigned short As[128 * 32];
    __shared__ unsigned short Bs[128 * 32];
    const int tid = threadIdx.x;
    const int wave = tid >> 6, lane = tid & 63;
    const int bm = blockIdx.y * 128, bn = blockIdx.x * 128;
    const int wm = (wave >> 1) * 64, wn = (wave & 1) * 64;
    const int lr = lane & 15, kh = lane >> 4;

    f32x4 acc[4][4] = {};

    const unsigned short* Arow = A + (size_t)bm * lda;
    const unsigned short* Brow = B + (size_t)bn * ldb;

    for (int kt = 0; kt < K; kt += 32) {
        #pragma unroll
        for (int it = 0; it < 2; ++it) {
            int rbase = it * 64 + wave * 16;
            int row = rbase + (lane >> 2);
            int c8 = (lane & 3) * 8;
            __builtin_amdgcn_global_load_lds(
                (const __attribute__((address_space(1))) unsigned int*)(Arow + (size_t)row * lda + kt + c8),
                (__attribute__((address_space(3))) unsigned int*)(As + rbase * 32),
                16, 0, 0);
            __builtin_amdgcn_global_load_lds(
                (const __attribute__((address_space(1))) unsigned int*)(Brow + (size_t)row * ldb + kt + c8),
                (__attribute__((address_space(3))) unsigned int*)(Bs + rbase * 32),
                16, 0, 0);
        }
        __syncthreads();

        bf16x8 af[4], bfr[4];
        #pragma unroll
        for (int i = 0; i < 4; ++i)
            af[i] = *(const bf16x8*)&As[(wm + i * 16 + lr) * 32 + kh * 8];
        #pragma unroll
        for (int j = 0; j < 4; ++j)
            bfr[j] = *(const bf16x8*)&Bs[(wn + j * 16 + lr) * 32 + kh * 8];
        #pragma unroll
        for (int i = 0; i < 4; ++i)
            #pragma unroll
            for (int j = 0; j < 4; ++j)
                acc[i][j] = __builtin_amdgcn_mfma_f32_16x16x32_bf16(af[i], bfr[j], acc[i][j], 0, 0, 0);
        __syncthreads();
    }

    #pragma unroll
    for (int i = 0; i < 4; ++i) {
        #pragma unroll
        for (int j = 0; j < 4; ++j) {
            #pragma unroll
            for (int r = 0; r < 4; ++r) {
                int row = bm + wm + i * 16 + kh * 4 + r;
                int col = bn + wn + j * 16 + lr;
                float v = acc[i][j][r];
                if (bias) v += bias[col];
                if (act == 1) v = softplusf(v);
                if (Rres) v += Rres[(size_t)row * ldc + col];
                C[((size_t)row * ldc + col) * cstride] = v;
            }
        }
    }
}

// split-K skinny GEMM: Part[ks] = aconv16[bm:bm+128, ks*192:(ks+1)*192] @ Wcat16^T
__global__ __launch_bounds__(256) void gemm_skinny_bf16(
    const unsigned short* __restrict__ A, const unsigned short* __restrict__ B,
    float* __restrict__ Part)
{
    __shared__ unsigned short As[128 * 32];
    __shared__ unsigned short Bs[128 * 32];
    const int tid = threadIdx.x;
    const int wave = tid >> 6, lane = tid & 63;
    const int bm = blockIdx.x * 128;
    const int ks = blockIdx.y;
    const int k0 = ks * KSL;
    const int wm = (wave >> 1) * 64, wn = (wave & 1) * 64;
    const int lr = lane & 15, kh = lane >> 4;

    f32x4 acc[4][4] = {};

    const unsigned short* Arow = A + (size_t)bm * DM;
    const unsigned short* Brow = B;   // 128 x DM

    for (int kt = 0; kt < KSL; kt += 32) {
        #pragma unroll
        for (int it = 0; it < 2; ++it) {
            int rbase = it * 64 + wave * 16;
            int row = rbase + (lane >> 2);
            int c8 = (lane & 3) * 8;
            __builtin_amdgcn_global_load_lds(
                (const __attribute__((address_space(1))) unsigned int*)(Arow + (size_t)row * DM + k0 + kt + c8),
                (__attribute__((address_space(3))) unsigned int*)(As + rbase * 32),
                16, 0, 0);
            __builtin_amdgcn_global_load_lds(
                (const __attribute__((address_space(1))) unsigned int*)(Brow + (size_t)row * DM + k0 + kt + c8),
                (__attribute__((address_space(3))) unsigned int*)(Bs + rbase * 32),
                16, 0, 0);
        }
        __syncthreads();

        bf16x8 af[4], bfr[4];
        #pragma unroll
        for (int i = 0; i < 4; ++i)
            af[i] = *(const bf16x8*)&As[(wm + i * 16 + lr) * 32 + kh * 8];
        #pragma unroll
        for (int j = 0; j < 4; ++j)
            bfr[j] = *(const bf16x8*)&Bs[(wn + j * 16 + lr) * 32 + kh * 8];
        #pragma unroll
        for (int i = 0; i < 4; ++i)
            #pragma unroll
            for (int j = 0; j < 4; ++j)
                acc[i][j] = __builtin_amdgcn_mfma_f32_16x16x32_bf16(af[i], bfr[j], acc[i][j], 0, 0, 0);
        __syncthreads();
    }

    float* out = Part + (size_t)ks * TT * NW;
    #pragma unroll
    for (int i = 0; i < 4; ++i) {
        #pragma unroll
        for (int j = 0; j < 4; ++j) {
            #pragma unroll
            for (int r = 0; r < 4; ++r) {
                int row = bm + wm + i * 16 + kh * 4 + r;
                int col = wn + j * 16 + lr;
                out[(size_t)row * NW + col] = acc[i][j][r];
            }
        }
    }
}

// sum KS partials -> BCD f32; cols 32..127 also -> dd16 bf16
__global__ void skinny_reduce(const float* __restrict__ Part,
                              float* __restrict__ BCD, unsigned short* __restrict__ dd16)
{
    int idx = blockIdx.x * 256 + threadIdx.x;     // over TT*NW
    float s = 0.f;
    #pragma unroll
    for (int ks = 0; ks < KS; ++ks)
        s += Part[(size_t)ks * TT * NW + idx];
    BCD[idx] = s;
    int col = idx & (NW - 1);
    if (col >= 32)
        dd16[(size_t)(idx >> 7) * DD + (col - 32)] = f2bf(s);
}

// causal depthwise conv (K=4) + silu; emits dav.y (f32, scan) and bf16 (skinny GEMM)
__global__ void conv_silu_kernel(const float* __restrict__ proj, const float* __restrict__ cw,
                                 const float* __restrict__ cb, float2* __restrict__ dav,
                                 unsigned short* __restrict__ aconv16)
{
    int t = blockIdx.x;
    int d = blockIdx.y * 256 + threadIdx.x;
    int p = t & (SS - 1);
    float acc = cb[d];
    #pragma unroll
    for (int j = 0; j < KC; ++j) {
        int pp = p - (KC - 1) + j;
        if (pp >= 0)
            acc += cw[d * KC + j] * proj[(size_t)(t - (KC - 1) + j) * (2 * DM) + d];
    }
    float v = siluf(acc);
    dav[(size_t)t * DM + d].y = v;
    aconv16[(size_t)t * DM + d] = f2bf(v);
}

// pack [WB;WC;W1] -> Wcat16[l][128][DM] (bf16)
__global__ void concat_w_kernel(const float* __restrict__ WB, const float* __restrict__ WC,
                                const float* __restrict__ W1, unsigned short* __restrict__ Wcat16)
{
    int l = blockIdx.y;
    int row = blockIdx.x;
    const float* src;
    if (row < 16)      src = WB + (size_t)l * DS * DM + (size_t)row * DM;
    else if (row < 32) src = WC + (size_t)l * DS * DM + (size_t)(row - 16) * DM;
    else               src = W1 + (size_t)l * DD * DM + (size_t)(row - 32) * DM;
    unsigned short* dst = Wcat16 + ((size_t)l * NW + row) * DM;
    for (int i = threadIdx.x; i < DM / 4; i += 256) {
        float4 v = ((const float4*)src)[i];
        us4 u = { f2bf(v.x), f2bf(v.y), f2bf(v.z), f2bf(v.w) };
        *(us4*)(dst + i * 4) = u;
    }
}

// ---- chunk-parallel selective scan: thread-per-d, s-states in registers ----
// dav[t][d] = {delta(softplus'd), aconv}; one 8B load per t-step.
__global__ __launch_bounds__(256) void scan_pass1(
    const float2* __restrict__ dav,
    const float* __restrict__ BCD, const float* __restrict__ Amat,
    float2* __restrict__ PQ)
{
    __shared__ float4 sB4[CL][DS / 4];
    int b = blockIdx.z, c = blockIdx.y;
    int d = blockIdx.x * 256 + threadIdx.x;
    size_t rowbase = (size_t)b * SS + (size_t)c * CL;

    for (int i = threadIdx.x; i < CL * DS; i += 256)
        ((float*)sB4)[i] = BCD[(rowbase + (i >> 4)) * NW + (i & 15)];
    __syncthreads();

    float negA[DS], hid[DS];
    #pragma unroll
    for (int s = 0; s < DS; ++s) {
        negA[s] = -Amat[(size_t)d * DS + s];
        hid[s] = 0.f;
    }
    float cum = 0.f;

    const float2* pv = dav + rowbase * DM + d;
    for (int t = 0; t < CL; ++t) {
        float2 da = pv[(size_t)t * DM];
        float dt = da.x, av = da.y;
        cum += dt;
        float xv = dt * av;
        #pragma unroll
        for (int j = 0; j < DS / 4; ++j) {
            float4 bv = sB4[t][j];
            hid[4*j+0] = __expf(dt * negA[4*j+0]) * hid[4*j+0] + xv * bv.x;
            hid[4*j+1] = __expf(dt * negA[4*j+1]) * hid[4*j+1] + xv * bv.y;
            hid[4*j+2] = __expf(dt * negA[4*j+2]) * hid[4*j+2] + xv * bv.z;
            hid[4*j+3] = __expf(dt * negA[4*j+3]) * hid[4*j+3] + xv * bv.w;
        }
    }
    float2* out = PQ + ((size_t)(b * NCH + c) * DM + d) * DS;
    #pragma unroll
    for (int s = 0; s < DS; ++s)
        out[s] = make_float2(__expf(cum * negA[s]), hid[s]);
}

// 49152 chains, NCH sequential chunk steps each; rewrites .x = carry-in
__global__ void scan_carry(float2* __restrict__ PQ)
{
    int idx = blockIdx.x * 256 + threadIdx.x;
    int b = idx / (DM * DS);
    int r = idx - b * (DM * DS);
    float carry = 0.f;
    for (int c = 0; c < NCH; ++c) {
        size_t o = (size_t)(b * NCH + c) * (DM * DS) + r;
        float2 pq = PQ[o];
        PQ[o].x = carry;
        carry = pq.x * carry + pq.y;
    }
}

// pass2: re-run seeded with carry; y16 = bf16((hid·Cm + Dp*av) * silu(gate))
__global__ __launch_bounds__(256) void scan_pass2(
    const float2* __restrict__ dav,
    const float* __restrict__ BCD,
    const float* __restrict__ proj, const float* __restrict__ Amat,
    const float* __restrict__ Dp, const float2* __restrict__ PQ,
    unsigned short* __restrict__ y)
{
    __shared__ float4 sB4[CL][DS / 4];
    __shared__ float4 sC4[CL][DS / 4];
    int b = blockIdx.z, c = blockIdx.y;
    int d = blockIdx.x * 256 + threadIdx.x;
    size_t rowbase = (size_t)b * SS + (size_t)c * CL;

    for (int i = threadIdx.x; i < CL * DS; i += 256) {
        size_t row = rowbase + (i >> 4);
        ((float*)sB4)[i] = BCD[row * NW + (i & 15)];
        ((float*)sC4)[i] = BCD[row * NW + 16 + (i & 15)];
    }
    __syncthreads();

    float negA[DS], hid[DS];
    const float2* pin = PQ + ((size_t)(b * NCH + c) * DM + d) * DS;
    #pragma unroll
    for (int s = 0; s < DS; ++s) {
        negA[s] = -Amat[(size_t)d * DS + s];
        hid[s] = pin[s].x;            // carry-in
    }
    float Dpd = Dp[d];

    const float2* pv = dav + rowbase * DM + d;
    const float* gp = proj + rowbase * (2 * DM) + DM + d;
    unsigned short* yp = y + rowbase * DM + d;

    for (int t = 0; t < CL; ++t) {
        float2 da = pv[(size_t)t * DM];
        float dt = da.x, av = da.y;
        float g  = gp[(size_t)t * (2 * DM)];
        float xv = dt * av;
        float acc0 = 0.f, acc1 = 0.f, acc2 = 0.f, acc3 = 0.f;
        #pragma unroll
        for (int j = 0; j < DS / 4; ++j) {
            float4 bv = sB4[t][j];
            float4 cv = sC4[t][j];
            hid[4*j+0] = __expf(dt * negA[4*j+0]) * hid[4*j+0] + xv * bv.x;
            hid[4*j+1] = __expf(dt * negA[4*j+1]) * hid[4*j+1] + xv * bv.y;
            hid[4*j+2] = __expf(dt * negA[4*j+2]) * hid[4*j+2] + xv * bv.z;
            hid[4*j+3] = __expf(dt * negA[4*j+3]) * hid[4*j+3] + xv * bv.w;
            acc0 += hid[4*j+0] * cv.x;
            acc1 += hid[4*j+1] * cv.y;
            acc2 += hid[4*j+2] * cv.z;
            acc3 += hid[4*j+3] * cv.w;
        }
        float contrib = (acc0 + acc1) + (acc2 + acc3);
        yp[(size_t)t * DM] = f2bf((contrib + Dpd * av) * siluf(g));
    }
}

// logits
__global__ void cls_kernel(const float* __restrict__ x, const float* __restrict__ W,
                           const float* __restrict__ bias, float* __restrict__ out)
{
    int t = blockIdx.x;
    int lane = threadIdx.x;
    const float* xr = x + (size_t)t * DI;
    float acc[NLAB];
    #pragma unroll
    for (int n = 0; n < NLAB; ++n) acc[n] = 0.f;
    for (int i = lane; i < DI; i += 64) {
        float xv = xr[i];
        #pragma unroll
        for (int n = 0; n < NLAB; ++n) acc[n] += xv * W[(size_t)n * DI + i];
    }
    #pragma unroll
    for (int n = 0; n < NLAB; ++n)
        #pragma unroll
        for (int m = 1; m < 64; m <<= 1) acc[n] += __shfl_xor(acc[n], m, 64);
    if (lane < NLAB) out[(size_t)t * NLAB + lane] = acc[lane] + bias[lane];
}

extern "C" void kernel_launch(void* const* d_in, const int* in_sizes, int n_in,
                              void* d_out, int out_size, void* d_ws, size_t ws_size,
                              hipStream_t stream)
{
    const int*   ids    = (const int*)d_in[0];
    const int*   mask   = (const int*)d_in[1];
    const float* emb    = (const float*)d_in[2];
    const float* norm_w = (const float*)d_in[3];
    const float* Wi     = (const float*)d_in[4];
    const float* conv_w = (const float*)d_in[5];
    const float* conv_b = (const float*)d_in[6];
    const float* sB_w   = (const float*)d_in[7];
    const float* sC_w   = (const float*)d_in[8];
    const float* sD1_w  = (const float*)d_in[9];
    const float* sD2_w  = (const float*)d_in[10];
    const float* Amat   = (const float*)d_in[11];
    const float* Dp     = (const float*)d_in[12];
    const float* out_w  = (const float*)d_in[13];
    const float* cls_w  = (const float*)d_in[14];
    const float* cls_b  = (const float*)d_in[15];
    float* logits = (float*)d_out;

    // workspace layout (float units)
    float* ws = (float*)d_ws;
    size_t off = 0;
    float* x     = ws + off; off += (size_t)TT * DI;
    float* proj  = ws + off; off += (size_t)TT * 2 * DM;
    float2* dav  = (float2*)(ws + off); off += (size_t)TT * DM * 2;  // {delta, aconv}
    float* BCD   = ws + off; off += (size_t)TT * NW;
    // Part (KS*TT*NW = 4.2M fl) and PQ (BB*NCH*DM*DS*2 = 6.3M fl) are liveness-disjoint: share.
    size_t scratch_sz = (size_t)BB * NCH * DM * DS * 2;
    size_t part_sz = (size_t)KS * TT * NW;
    if (part_sz > scratch_sz) scratch_sz = part_sz;
    float* Part  = ws + off;
    float2* PQ   = (float2*)(ws + off); off += scratch_sz;
    unsigned short* y16     = (unsigned short*)(ws + off); off += (size_t)TT * DM / 2;
    unsigned short* aconv16 = (unsigned short*)(ws + off); off += (size_t)TT * DM / 2;
    unsigned short* Wi16    = (unsigned short*)(ws + off); off += (size_t)NL * 2 * DM * DI / 2;
    unsigned short* Wo16    = (unsigned short*)(ws + off); off += (size_t)NL * DI * DM / 2;
    unsigned short* W216    = (unsigned short*)(ws + off); off += (size_t)NL * DM * DD / 2;
    unsigned short* dd16    = (unsigned short*)(ws + off); off += (size_t)TT * DD / 2;
    unsigned short* Wcat16  = (unsigned short*)(ws + off); off += (size_t)NL * NW * DM / 2;
    if (ws_size < off * sizeof(float)) return;  // fail loud

    // h16 overlays dav: h16 is dead after in_proj GEMM; dav written only after that.
    unsigned short* h16 = (unsigned short*)dav;

    embed_kernel<<<TT, DI / 4, 0, stream>>>(ids, mask, emb, x);
    concat_w_kernel<<<dim3(NW, NL), 256, 0, stream>>>(sB_w, sC_w, sD1_w, Wcat16);

    // whole-tensor weight conversions (all layers at once)
    f32_to_bf16<<<(NL * 2 * DM * DI / 8 + 255) / 256, 256, 0, stream>>>(Wi, Wi16, NL * 2 * DM * DI);
    f32_to_bf16<<<(NL * DI * DM / 8 + 255) / 256, 256, 0, stream>>>(out_w, Wo16, NL * DI * DM);
    f32_to_bf16<<<(NL * DM * DD / 8 + 255) / 256, 256, 0, stream>>>(sD2_w, W216, NL * DM * DD);

    for (int l = 0; l < NL; ++l) {
        const float* cw_l  = conv_w + (size_t)l * DM * KC;
        const float* cb_l  = conv_b + (size_t)l * DM;
        const float* A_l   = Amat  + (size_t)l * DM * DS;
        const float* Dp_l  = Dp    + (size_t)l * DM;
        const float* nw_l  = norm_w + (size_t)l * DI;
        const unsigned short* Wi16_l  = Wi16  + (size_t)l * 2 * DM * DI;
        const unsigned short* Wo16_l  = Wo16  + (size_t)l * DI * DM;
        const unsigned short* W216_l  = W216  + (size_t)l * DM * DD;
        const unsigned short* Wcat16_l = Wcat16 + (size_t)l * NW * DM;

        rmsnorm_kernel<<<TT, 256, 0, stream>>>(x, nw_l, h16);

        // proj = h @ Wi^T : M=TT, N=2*DM, K=DI  (bf16 MFMA)
        gemm_bf16<<<dim3(2 * DM / 128, TT / 128), 256, 0, stream>>>(
            h16, Wi16_l, nullptr, nullptr, proj, TT, 2 * DM, DI, DI, DI, 2 * DM, 0, 1);

        conv_silu_kernel<<<dim3(TT, DM / 256), 256, 0, stream>>>(proj, cw_l, cb_l, dav, aconv16);

        // BCD = aconv @ Wcat^T (Bm | Cm | dd1), split-K MFMA + reduce
        gemm_skinny_bf16<<<dim3(TT / 128, KS), 256, 0, stream>>>(aconv16, Wcat16_l, Part);
        skinny_reduce<<<TT * NW / 256, 256, 0, stream>>>(Part, BCD, dd16);

        // delta = softplus(Dp + dd1 @ W2^T) -> dav.x  (cstride=2)
        gemm_bf16<<<dim3(DM / 128, TT / 128), 256, 0, stream>>>(
            dd16, W216_l, nullptr, Dp_l, (float*)dav, TT, DM, DD, DD, DD, DM, 1, 2);

        // chunk-parallel scan (thread-per-d)
        scan_pass1<<<dim3(DM / 256, NCH, BB), 256, 0, stream>>>(dav, BCD, A_l, PQ);
        scan_carry<<<BB * DM * DS / 256, 256, 0, stream>>>(PQ);
        scan_pass2<<<dim3(DM / 256, NCH, BB), 256, 0, stream>>>(
            dav, BCD, proj, A_l, Dp_l, PQ, y16);

        // x = x + y @ Wo^T : M=TT, N=DI, K=DM  (bf16 MFMA)
        gemm_bf16<<<dim3(DI / 128, TT / 128), 256, 0, stream>>>(
            y16, Wo16_l, x, nullptr, x, TT, DI, DM, DM, DM, DI, 0, 1);
    }

    cls_kernel<<<TT, 64, 0, stream>>>(x, cls_w, cls_b, logits);
}